// Round 1
// baseline (780.372 us; speedup 1.0000x reference)
//
#include <hip/hip_runtime.h>
#include <hip/hip_bf16.h>
#include <math.h>

// GCN: h1 = relu(Agg(x@W1)+b1); h2 = relu(Agg(h1@W2)+b2); pooled = segment_mean(h2);
// out = log_softmax(relu(pooled@fc1+b)@fc2+b)
// Agg built as CSR-by-dst each launch (graph-capture safe, ws re-poisoned every call).

#define D_FEAT 128

__global__ void hist_kernel(const int* __restrict__ edges, int* __restrict__ counts, int E) {
    int i = blockIdx.x * blockDim.x + threadIdx.x;
    if (i < E) atomicAdd(&counts[edges[E + i]], 1);
}

__global__ void dis_kernel(const int* __restrict__ counts, float* __restrict__ dis, int N) {
    int i = blockIdx.x * blockDim.x + threadIdx.x;
    if (i < N) dis[i] = rsqrtf((float)counts[i] + 1.0f);  // +1 = self loop
}

// exclusive scan phase 1: per-block (1024 elems) scan
__global__ void scan1_kernel(const int* __restrict__ counts, int* __restrict__ rowptr,
                             int* __restrict__ blockSums, int N) {
    __shared__ int sdata[256];
    int t = threadIdx.x;
    int base = blockIdx.x * 1024 + t * 4;
    int c[4];
#pragma unroll
    for (int i = 0; i < 4; ++i) c[i] = (base + i < N) ? counts[base + i] : 0;
    int tsum = c[0] + c[1] + c[2] + c[3];
    sdata[t] = tsum;
    __syncthreads();
    for (int d = 1; d < 256; d <<= 1) {
        int v = (t >= d) ? sdata[t - d] : 0;
        __syncthreads();
        sdata[t] += v;
        __syncthreads();
    }
    int run = sdata[t] - tsum;  // exclusive prefix of this thread
#pragma unroll
    for (int i = 0; i < 4; ++i) {
        if (base + i < N) rowptr[base + i] = run;
        run += c[i];
    }
    if (t == 255) blockSums[blockIdx.x] = sdata[255];
}

// phase 2: scan the (<=128) block sums
__global__ void scan2_kernel(const int* __restrict__ blockSums, int* __restrict__ blockOffs, int nb) {
    __shared__ int sdata[128];
    int t = threadIdx.x;
    int v = (t < nb) ? blockSums[t] : 0;
    sdata[t] = v;
    __syncthreads();
    for (int d = 1; d < 128; d <<= 1) {
        int u = (t >= d) ? sdata[t - d] : 0;
        __syncthreads();
        sdata[t] += u;
        __syncthreads();
    }
    if (t < nb) blockOffs[t] = sdata[t] - v;
}

__global__ void scan3_kernel(int* __restrict__ rowptr, const int* __restrict__ blockOffs,
                             int N, int E) {
    int i = blockIdx.x * blockDim.x + threadIdx.x;
    if (i < N) rowptr[i] += blockOffs[i >> 10];
    if (i == 0) rowptr[N] = E;
}

__global__ void scatter_kernel(const int* __restrict__ edges, const int* __restrict__ rowptr,
                               int* __restrict__ cursor, const float* __restrict__ dis,
                               int* __restrict__ csr_src, float* __restrict__ csr_norm, int E) {
    int i = blockIdx.x * blockDim.x + threadIdx.x;
    if (i < E) {
        int s = edges[i];
        int d = edges[E + i];
        int pos = rowptr[d] + atomicAdd(&cursor[d], 1);
        csr_src[pos] = s;
        csr_norm[pos] = dis[s] * dis[d];
    }
}

// Y[nrows,128] = X[nrows,128] @ W[128,128]. nrows % 16 == 0.
// Block: 256 threads, 16 rows. Thread (j = t&127, p = t>>7) computes rows {p,p+2,...,p+14} at col j.
__global__ void __launch_bounds__(256) gemm128_kernel(const float* __restrict__ X,
                                                      const float* __restrict__ W,
                                                      float* __restrict__ Y, int nrows) {
    __shared__ float xs[16][128];   // 8 KB
    __shared__ float wsm[32][128];  // 16 KB, K-chunk of W
    int t = threadIdx.x;
    int j = t & 127;
    int p = t >> 7;
    int row0 = blockIdx.x * 16;

    // stage 16 rows of X (2048 floats) with float4
    {
        const float4* xsrc = (const float4*)(X + (size_t)row0 * 128);
        float4* xdst = (float4*)(&xs[0][0]);
#pragma unroll
        for (int i = 0; i < 2; ++i) xdst[t * 2 + i] = xsrc[t * 2 + i];
    }
    float acc[8];
#pragma unroll
    for (int r = 0; r < 8; ++r) acc[r] = 0.f;

    for (int k0 = 0; k0 < 128; k0 += 32) {
        __syncthreads();  // xs ready (first iter) / wsm consumers done (later iters)
        const float4* wsrc = (const float4*)(W + (size_t)k0 * 128);
        float4* wdst = (float4*)(&wsm[0][0]);
#pragma unroll
        for (int i = 0; i < 4; ++i) wdst[t * 4 + i] = wsrc[t * 4 + i];
        __syncthreads();
#pragma unroll
        for (int kk = 0; kk < 32; ++kk) {
            float w = wsm[kk][j];
#pragma unroll
            for (int r = 0; r < 8; ++r) acc[r] = fmaf(xs[r * 2 + p][k0 + kk], w, acc[r]);
        }
    }
#pragma unroll
    for (int r = 0; r < 8; ++r)
        Y[(size_t)(row0 + r * 2 + p) * 128 + j] = acc[r];
}

// One wave per destination node; lane holds 2 features (float2). No atomics.
__global__ void __launch_bounds__(256) agg_kernel(const float* __restrict__ H,
                                                  const int* __restrict__ rowptr,
                                                  const int* __restrict__ csr_src,
                                                  const float* __restrict__ csr_norm,
                                                  const float* __restrict__ dis,
                                                  const float* __restrict__ bias,
                                                  float* __restrict__ out, int N) {
    int v = (blockIdx.x * blockDim.x + threadIdx.x) >> 6;
    int lane = threadIdx.x & 63;
    if (v >= N) return;
    int r0 = rowptr[v], r1 = rowptr[v + 1];
    float wself = dis[v];
    wself *= wself;
    float2 hv = ((const float2*)(H + (size_t)v * 128))[lane];
    float ax = wself * hv.x, ay = wself * hv.y;
    int e = r0;
    for (; e + 2 <= r1; e += 2) {  // 2-edge unroll for MLP
        int s0 = csr_src[e], s1 = csr_src[e + 1];
        float w0 = csr_norm[e], w1 = csr_norm[e + 1];
        float2 a = ((const float2*)(H + (size_t)s0 * 128))[lane];
        float2 b = ((const float2*)(H + (size_t)s1 * 128))[lane];
        ax += w0 * a.x + w1 * b.x;
        ay += w0 * a.y + w1 * b.y;
    }
    if (e < r1) {
        int s0 = csr_src[e];
        float w0 = csr_norm[e];
        float2 a = ((const float2*)(H + (size_t)s0 * 128))[lane];
        ax += w0 * a.x;
        ay += w0 * a.y;
    }
    float2 b = ((const float2*)bias)[lane];
    float ox = fmaxf(ax + b.x, 0.f);
    float oy = fmaxf(ay + b.y, 0.f);
    ((float2*)(out + (size_t)v * 128))[lane] = make_float2(ox, oy);
}

__device__ __forceinline__ int lower_bound_i(const int* a, int n, int key) {
    int lo = 0, hi = n;
    while (lo < hi) {
        int mid = (lo + hi) >> 1;
        if (a[mid] < key) lo = mid + 1;
        else hi = mid;
    }
    return lo;
}

// one block (128 thr) per graph; batch is sorted
__global__ void pool_kernel(const float* __restrict__ H, const int* __restrict__ batch,
                            float* __restrict__ pooled, int N) {
    __shared__ int range[2];
    int g = blockIdx.x;
    if (threadIdx.x == 0) range[0] = lower_bound_i(batch, N, g);
    if (threadIdx.x == 1) range[1] = lower_bound_i(batch, N, g + 1);
    __syncthreads();
    int lo = range[0], hi = range[1];
    int j = threadIdx.x;
    float s = 0.f;
    for (int v = lo; v < hi; ++v) s += H[(size_t)v * 128 + j];
    float cnt = (float)(hi - lo);
    pooled[g * 128 + j] = s / fmaxf(cnt, 1.0f);
}

// one block (128 thr) per graph: relu(pooled@fc1+b1) @ fc2 + b2 -> log_softmax(2)
__global__ void head_kernel(const float* __restrict__ pooled, const float* __restrict__ fc1w,
                            const float* __restrict__ fc1b, const float* __restrict__ fc2w,
                            const float* __restrict__ fc2b, float* __restrict__ out) {
    __shared__ float p[128];
    __shared__ float r0[128], r1[128];
    int g = blockIdx.x;
    int j = threadIdx.x;
    p[j] = pooled[g * 128 + j];
    __syncthreads();
    float acc = fc1b[j];
    for (int k = 0; k < 128; ++k) acc = fmaf(p[k], fc1w[k * 128 + j], acc);
    float gv = fmaxf(acc, 0.f);
    r0[j] = gv * fc2w[j * 2 + 0];
    r1[j] = gv * fc2w[j * 2 + 1];
    __syncthreads();
    for (int s = 64; s > 0; s >>= 1) {
        if (j < s) {
            r0[j] += r0[j + s];
            r1[j] += r1[j + s];
        }
        __syncthreads();
    }
    if (j == 0) {
        float l0 = r0[0] + fc2b[0];
        float l1 = r1[0] + fc2b[1];
        float m = fmaxf(l0, l1);
        float lse = m + logf(expf(l0 - m) + expf(l1 - m));
        out[g * 2 + 0] = l0 - lse;
        out[g * 2 + 1] = l1 - lse;
    }
}

extern "C" void kernel_launch(void* const* d_in, const int* in_sizes, int n_in,
                              void* d_out, int out_size, void* d_ws, size_t ws_size,
                              hipStream_t stream) {
    const float* x    = (const float*)d_in[0];
    const int* edges  = (const int*)d_in[1];
    const int* batch  = (const int*)d_in[2];
    const float* W1   = (const float*)d_in[3];
    const float* b1   = (const float*)d_in[4];
    const float* W2   = (const float*)d_in[5];
    const float* b2   = (const float*)d_in[6];
    const float* fc1w = (const float*)d_in[7];
    const float* fc1b = (const float*)d_in[8];
    const float* fc2w = (const float*)d_in[9];
    const float* fc2b = (const float*)d_in[10];
    float* out = (float*)d_out;

    int N = in_sizes[2];        // 100000
    int E = in_sizes[1] / 2;    // 1600000
    int G = out_size / 2;       // 1024

    char* ws = (char*)d_ws;
    size_t off = 0;
    auto alloc = [&](size_t bytes) -> char* {
        char* ptr = ws + off;
        off += (bytes + 255) & ~(size_t)255;
        return ptr;
    };
    int* counts    = (int*)alloc((size_t)N * 4);
    float* dis     = (float*)alloc((size_t)N * 4);
    int* rowptr    = (int*)alloc((size_t)(N + 1) * 4);
    int* cursor    = (int*)alloc((size_t)N * 4);
    int* csr_src   = (int*)alloc((size_t)E * 4);
    float* csr_nrm = (float*)alloc((size_t)E * 4);
    int* blockSums = (int*)alloc(1024 * 4);
    int* blockOffs = (int*)alloc(1024 * 4);
    float* bufA    = (float*)alloc((size_t)N * D_FEAT * 4);
    float* bufB    = (float*)alloc((size_t)N * D_FEAT * 4);
    float* pooled  = (float*)alloc((size_t)G * D_FEAT * 4);

    hipMemsetAsync(counts, 0, (size_t)N * 4, stream);
    hipMemsetAsync(cursor, 0, (size_t)N * 4, stream);

    const int tb = 256;
    int gE = (E + tb - 1) / tb;
    int gN = (N + tb - 1) / tb;
    int nb = (N + 1023) / 1024;  // 98 (<=128 required by scan2)

    hist_kernel<<<gE, tb, 0, stream>>>(edges, counts, E);
    dis_kernel<<<gN, tb, 0, stream>>>(counts, dis, N);
    scan1_kernel<<<nb, 256, 0, stream>>>(counts, rowptr, blockSums, N);
    scan2_kernel<<<1, 128, 0, stream>>>(blockSums, blockOffs, nb);
    scan3_kernel<<<gN, tb, 0, stream>>>(rowptr, blockOffs, N, E);
    scatter_kernel<<<gE, tb, 0, stream>>>(edges, rowptr, cursor, dis, csr_src, csr_nrm, E);

    int gAgg = (N * 64 + tb - 1) / tb;
    gemm128_kernel<<<N / 16, 256, 0, stream>>>(x, W1, bufA, N);
    agg_kernel<<<gAgg, tb, 0, stream>>>(bufA, rowptr, csr_src, csr_nrm, dis, b1, bufB, N);
    gemm128_kernel<<<N / 16, 256, 0, stream>>>(bufB, W2, bufA, N);
    agg_kernel<<<gAgg, tb, 0, stream>>>(bufA, rowptr, csr_src, csr_nrm, dis, b2, bufB, N);
    pool_kernel<<<G, 128, 0, stream>>>(bufB, batch, pooled, N);
    head_kernel<<<G, 128, 0, stream>>>(pooled, fc1w, fc1b, fc2w, fc2b, out);
}

// Round 2
// 709.560 us; speedup vs baseline: 1.0998x; 1.0998x over previous
//
#include <hip/hip_runtime.h>
#include <hip/hip_bf16.h>
#include <hip/hip_fp16.h>
#include <math.h>

// GCN: h1 = relu(Agg(x@W1)+b1); h2 = relu(Agg(h1@W2)+b2); pooled = segment_mean(h2);
// out = log_softmax(relu(pooled@fc1+b)@fc2+b)
// Activations (N x 128 buffers) stored as fp16 to halve gather bandwidth in agg;
// all arithmetic and weights stay fp32 (fp16 storage noise ~0.03% << 1.5e-2 threshold).

#define D_FEAT 128

__global__ void hist_kernel(const int* __restrict__ edges, int* __restrict__ counts, int E) {
    int i = blockIdx.x * blockDim.x + threadIdx.x;
    if (i < E) atomicAdd(&counts[edges[E + i]], 1);
}

__global__ void dis_kernel(const int* __restrict__ counts, float* __restrict__ dis, int N) {
    int i = blockIdx.x * blockDim.x + threadIdx.x;
    if (i < N) dis[i] = rsqrtf((float)counts[i] + 1.0f);  // +1 = self loop
}

// exclusive scan phase 1: per-block (1024 elems) scan
__global__ void scan1_kernel(const int* __restrict__ counts, int* __restrict__ rowptr,
                             int* __restrict__ blockSums, int N) {
    __shared__ int sdata[256];
    int t = threadIdx.x;
    int base = blockIdx.x * 1024 + t * 4;
    int c[4];
#pragma unroll
    for (int i = 0; i < 4; ++i) c[i] = (base + i < N) ? counts[base + i] : 0;
    int tsum = c[0] + c[1] + c[2] + c[3];
    sdata[t] = tsum;
    __syncthreads();
    for (int d = 1; d < 256; d <<= 1) {
        int v = (t >= d) ? sdata[t - d] : 0;
        __syncthreads();
        sdata[t] += v;
        __syncthreads();
    }
    int run = sdata[t] - tsum;  // exclusive prefix of this thread
#pragma unroll
    for (int i = 0; i < 4; ++i) {
        if (base + i < N) rowptr[base + i] = run;
        run += c[i];
    }
    if (t == 255) blockSums[blockIdx.x] = sdata[255];
}

// phase 2: scan the (<=128) block sums
__global__ void scan2_kernel(const int* __restrict__ blockSums, int* __restrict__ blockOffs, int nb) {
    __shared__ int sdata[128];
    int t = threadIdx.x;
    int v = (t < nb) ? blockSums[t] : 0;
    sdata[t] = v;
    __syncthreads();
    for (int d = 1; d < 128; d <<= 1) {
        int u = (t >= d) ? sdata[t - d] : 0;
        __syncthreads();
        sdata[t] += u;
        __syncthreads();
    }
    if (t < nb) blockOffs[t] = sdata[t] - v;
}

// finalize rowptr and seed cursor = rowptr (scatter then needs only one atomic)
__global__ void scan3_kernel(int* __restrict__ rowptr, int* __restrict__ cursor,
                             const int* __restrict__ blockOffs, int N, int E) {
    int i = blockIdx.x * blockDim.x + threadIdx.x;
    if (i < N) {
        int r = rowptr[i] + blockOffs[i >> 10];
        rowptr[i] = r;
        cursor[i] = r;
    }
    if (i == 0) rowptr[N] = E;
}

__global__ void scatter_kernel(const int* __restrict__ edges,
                               int* __restrict__ cursor, const float* __restrict__ dis,
                               int* __restrict__ csr_src, float* __restrict__ csr_norm, int E) {
    int i = blockIdx.x * blockDim.x + threadIdx.x;
    if (i < E) {
        int s = edges[i];
        int d = edges[E + i];
        int pos = atomicAdd(&cursor[d], 1);
        csr_src[pos] = s;
        csr_norm[pos] = dis[s] * dis[d];
    }
}

// Y[nrows,128] = X[nrows,128] @ W[128,128]. nrows % 16 == 0. fp32 math, fp16 output.
// Block: 256 threads, 16 rows. Thread (j = t&127, p = t>>7) computes rows {p,p+2,...,p+14} at col j.
template <bool HALF_IN>
__global__ void __launch_bounds__(256) gemm128_kernel(const void* __restrict__ Xv,
                                                      const float* __restrict__ W,
                                                      __half* __restrict__ Y, int nrows) {
    __shared__ float xs[16][128];   // 8 KB
    __shared__ float wsm[32][128];  // 16 KB, K-chunk of W
    int t = threadIdx.x;
    int j = t & 127;
    int p = t >> 7;
    int row0 = blockIdx.x * 16;

    // stage 16 rows of X (2048 elems) into LDS as fp32
    if (HALF_IN) {
        const __half2* xsrc = (const __half2*)((const __half*)Xv + (size_t)row0 * 128);
        float* xflat = &xs[0][0];
#pragma unroll
        for (int i = 0; i < 4; ++i) {
            int idx = t * 4 + i;          // half2 index, covers elems [8t, 8t+8)
            float2 f = __half22float2(xsrc[idx]);
            xflat[2 * idx] = f.x;
            xflat[2 * idx + 1] = f.y;
        }
    } else {
        const float4* xsrc = (const float4*)((const float*)Xv + (size_t)row0 * 128);
        float4* xdst = (float4*)(&xs[0][0]);
#pragma unroll
        for (int i = 0; i < 2; ++i) xdst[t * 2 + i] = xsrc[t * 2 + i];
    }
    float acc[8];
#pragma unroll
    for (int r = 0; r < 8; ++r) acc[r] = 0.f;

    for (int k0 = 0; k0 < 128; k0 += 32) {
        __syncthreads();  // xs ready (first iter) / wsm consumers done (later iters)
        const float4* wsrc = (const float4*)(W + (size_t)k0 * 128);
        float4* wdst = (float4*)(&wsm[0][0]);
#pragma unroll
        for (int i = 0; i < 4; ++i) wdst[t * 4 + i] = wsrc[t * 4 + i];
        __syncthreads();
#pragma unroll
        for (int kk = 0; kk < 32; ++kk) {
            float w = wsm[kk][j];
#pragma unroll
            for (int r = 0; r < 8; ++r) acc[r] = fmaf(xs[r * 2 + p][k0 + kk], w, acc[r]);
        }
    }
#pragma unroll
    for (int r = 0; r < 8; ++r)
        Y[(size_t)(row0 + r * 2 + p) * 128 + j] = __float2half(acc[r]);
}

// One wave per destination node; lane holds 2 features (half2 = 4B/edge/lane). No atomics.
__global__ void __launch_bounds__(256) agg_kernel(const __half* __restrict__ H,
                                                  const int* __restrict__ rowptr,
                                                  const int* __restrict__ csr_src,
                                                  const float* __restrict__ csr_norm,
                                                  const float* __restrict__ dis,
                                                  const float* __restrict__ bias,
                                                  __half* __restrict__ out, int N) {
    int v = (blockIdx.x * blockDim.x + threadIdx.x) >> 6;
    int lane = threadIdx.x & 63;
    if (v >= N) return;
    int r0 = rowptr[v], r1 = rowptr[v + 1];
    float wself = dis[v];
    wself *= wself;
    float2 hv = __half22float2(((const __half2*)(H + (size_t)v * 128))[lane]);
    float ax = wself * hv.x, ay = wself * hv.y;
    int e = r0;
    for (; e + 4 <= r1; e += 4) {  // 4-edge unroll for MLP
        int s0 = csr_src[e], s1 = csr_src[e + 1], s2 = csr_src[e + 2], s3 = csr_src[e + 3];
        float w0 = csr_norm[e], w1 = csr_norm[e + 1], w2 = csr_norm[e + 2], w3 = csr_norm[e + 3];
        float2 a = __half22float2(((const __half2*)(H + (size_t)s0 * 128))[lane]);
        float2 b = __half22float2(((const __half2*)(H + (size_t)s1 * 128))[lane]);
        float2 c = __half22float2(((const __half2*)(H + (size_t)s2 * 128))[lane]);
        float2 d = __half22float2(((const __half2*)(H + (size_t)s3 * 128))[lane]);
        ax += w0 * a.x + w1 * b.x + w2 * c.x + w3 * d.x;
        ay += w0 * a.y + w1 * b.y + w2 * c.y + w3 * d.y;
    }
    for (; e < r1; ++e) {
        int s0 = csr_src[e];
        float w0 = csr_norm[e];
        float2 a = __half22float2(((const __half2*)(H + (size_t)s0 * 128))[lane]);
        ax += w0 * a.x;
        ay += w0 * a.y;
    }
    float2 b = ((const float2*)bias)[lane];
    float ox = fmaxf(ax + b.x, 0.f);
    float oy = fmaxf(ay + b.y, 0.f);
    ((__half2*)(out + (size_t)v * 128))[lane] = __floats2half2_rn(ox, oy);
}

__device__ __forceinline__ int lower_bound_i(const int* a, int n, int key) {
    int lo = 0, hi = n;
    while (lo < hi) {
        int mid = (lo + hi) >> 1;
        if (a[mid] < key) lo = mid + 1;
        else hi = mid;
    }
    return lo;
}

// one block (128 thr) per graph; batch is sorted
__global__ void pool_kernel(const __half* __restrict__ H, const int* __restrict__ batch,
                            float* __restrict__ pooled, int N) {
    __shared__ int range[2];
    int g = blockIdx.x;
    if (threadIdx.x == 0) range[0] = lower_bound_i(batch, N, g);
    if (threadIdx.x == 1) range[1] = lower_bound_i(batch, N, g + 1);
    __syncthreads();
    int lo = range[0], hi = range[1];
    int j = threadIdx.x;
    float s = 0.f;
    for (int v = lo; v < hi; ++v) s += __half2float(H[(size_t)v * 128 + j]);
    float cnt = (float)(hi - lo);
    pooled[g * 128 + j] = s / fmaxf(cnt, 1.0f);
}

// one block (128 thr) per graph: relu(pooled@fc1+b1) @ fc2 + b2 -> log_softmax(2)
__global__ void head_kernel(const float* __restrict__ pooled, const float* __restrict__ fc1w,
                            const float* __restrict__ fc1b, const float* __restrict__ fc2w,
                            const float* __restrict__ fc2b, float* __restrict__ out) {
    __shared__ float p[128];
    __shared__ float r0[128], r1[128];
    int g = blockIdx.x;
    int j = threadIdx.x;
    p[j] = pooled[g * 128 + j];
    __syncthreads();
    float acc = fc1b[j];
    for (int k = 0; k < 128; ++k) acc = fmaf(p[k], fc1w[k * 128 + j], acc);
    float gv = fmaxf(acc, 0.f);
    r0[j] = gv * fc2w[j * 2 + 0];
    r1[j] = gv * fc2w[j * 2 + 1];
    __syncthreads();
    for (int s = 64; s > 0; s >>= 1) {
        if (j < s) {
            r0[j] += r0[j + s];
            r1[j] += r1[j + s];
        }
        __syncthreads();
    }
    if (j == 0) {
        float l0 = r0[0] + fc2b[0];
        float l1 = r1[0] + fc2b[1];
        float m = fmaxf(l0, l1);
        float lse = m + logf(expf(l0 - m) + expf(l1 - m));
        out[g * 2 + 0] = l0 - lse;
        out[g * 2 + 1] = l1 - lse;
    }
}

extern "C" void kernel_launch(void* const* d_in, const int* in_sizes, int n_in,
                              void* d_out, int out_size, void* d_ws, size_t ws_size,
                              hipStream_t stream) {
    const float* x    = (const float*)d_in[0];
    const int* edges  = (const int*)d_in[1];
    const int* batch  = (const int*)d_in[2];
    const float* W1   = (const float*)d_in[3];
    const float* b1   = (const float*)d_in[4];
    const float* W2   = (const float*)d_in[5];
    const float* b2   = (const float*)d_in[6];
    const float* fc1w = (const float*)d_in[7];
    const float* fc1b = (const float*)d_in[8];
    const float* fc2w = (const float*)d_in[9];
    const float* fc2b = (const float*)d_in[10];
    float* out = (float*)d_out;

    int N = in_sizes[2];        // 100000
    int E = in_sizes[1] / 2;    // 1600000
    int G = out_size / 2;       // 1024

    char* ws = (char*)d_ws;
    size_t off = 0;
    auto alloc = [&](size_t bytes) -> char* {
        char* ptr = ws + off;
        off += (bytes + 255) & ~(size_t)255;
        return ptr;
    };
    int* counts    = (int*)alloc((size_t)N * 4);
    float* dis     = (float*)alloc((size_t)N * 4);
    int* rowptr    = (int*)alloc((size_t)(N + 1) * 4);
    int* cursor    = (int*)alloc((size_t)N * 4);
    int* csr_src   = (int*)alloc((size_t)E * 4);
    float* csr_nrm = (float*)alloc((size_t)E * 4);
    int* blockSums = (int*)alloc(1024 * 4);
    int* blockOffs = (int*)alloc(1024 * 4);
    __half* bufA   = (__half*)alloc((size_t)N * D_FEAT * 2);
    __half* bufB   = (__half*)alloc((size_t)N * D_FEAT * 2);
    float* pooled  = (float*)alloc((size_t)G * D_FEAT * 4);

    hipMemsetAsync(counts, 0, (size_t)N * 4, stream);

    const int tb = 256;
    int gE = (E + tb - 1) / tb;
    int gN = (N + tb - 1) / tb;
    int nb = (N + 1023) / 1024;  // 98 (<=128 required by scan2)

    hist_kernel<<<gE, tb, 0, stream>>>(edges, counts, E);
    dis_kernel<<<gN, tb, 0, stream>>>(counts, dis, N);
    scan1_kernel<<<nb, 256, 0, stream>>>(counts, rowptr, blockSums, N);
    scan2_kernel<<<1, 128, 0, stream>>>(blockSums, blockOffs, nb);
    scan3_kernel<<<gN, tb, 0, stream>>>(rowptr, cursor, blockOffs, N, E);
    scatter_kernel<<<gE, tb, 0, stream>>>(edges, cursor, dis, csr_src, csr_nrm, E);

    int gAgg = (N * 64 + tb - 1) / tb;
    gemm128_kernel<false><<<N / 16, 256, 0, stream>>>((const void*)x, W1, bufA, N);
    agg_kernel<<<gAgg, tb, 0, stream>>>(bufA, rowptr, csr_src, csr_nrm, dis, b1, bufB, N);
    gemm128_kernel<true><<<N / 16, 256, 0, stream>>>((const void*)bufB, W2, bufA, N);
    agg_kernel<<<gAgg, tb, 0, stream>>>(bufA, rowptr, csr_src, csr_nrm, dis, b2, bufB, N);
    pool_kernel<<<G, 128, 0, stream>>>(bufB, batch, pooled, N);
    head_kernel<<<G, 128, 0, stream>>>(pooled, fc1w, fc1b, fc2w, fc2b, out);
}

// Round 3
// 526.864 us; speedup vs baseline: 1.4812x; 1.3468x over previous
//
#include <hip/hip_runtime.h>
#include <hip/hip_fp16.h>
#include <math.h>

// GCN: h1 = relu(Agg(x@W1)+b1); h2 = relu(Agg(h1@W2)+b2); pooled = segment_mean(h2);
// out = log_softmax(relu(pooled@fc1+b)@fc2+b)
// Activations stored fp16 (halves gather BW); GEMMs use fp16 MFMA w/ fp32 accum.
// CSR stores only src ids; norm recomputed in agg from L2-resident dis[].

#define D_FEAT 128

using half8  = __attribute__((ext_vector_type(8))) _Float16;
using half4  = __attribute__((ext_vector_type(4))) _Float16;
using half2v = __attribute__((ext_vector_type(2))) _Float16;
using floatx4 = __attribute__((ext_vector_type(4))) float;

__global__ void hist_kernel(const int* __restrict__ edges, int* __restrict__ counts, int E) {
    int i = blockIdx.x * blockDim.x + threadIdx.x;
    if (i < E) atomicAdd(&counts[edges[E + i]], 1);
}

__global__ void dis_kernel(const int* __restrict__ counts, float* __restrict__ dis, int N) {
    int i = blockIdx.x * blockDim.x + threadIdx.x;
    if (i < N) dis[i] = rsqrtf((float)counts[i] + 1.0f);  // +1 = self loop
}

// exclusive scan phase 1: per-block (1024 elems) scan
__global__ void scan1_kernel(const int* __restrict__ counts, int* __restrict__ rowptr,
                             int* __restrict__ blockSums, int N) {
    __shared__ int sdata[256];
    int t = threadIdx.x;
    int base = blockIdx.x * 1024 + t * 4;
    int c[4];
#pragma unroll
    for (int i = 0; i < 4; ++i) c[i] = (base + i < N) ? counts[base + i] : 0;
    int tsum = c[0] + c[1] + c[2] + c[3];
    sdata[t] = tsum;
    __syncthreads();
    for (int d = 1; d < 256; d <<= 1) {
        int v = (t >= d) ? sdata[t - d] : 0;
        __syncthreads();
        sdata[t] += v;
        __syncthreads();
    }
    int run = sdata[t] - tsum;
#pragma unroll
    for (int i = 0; i < 4; ++i) {
        if (base + i < N) rowptr[base + i] = run;
        run += c[i];
    }
    if (t == 255) blockSums[blockIdx.x] = sdata[255];
}

__global__ void scan2_kernel(const int* __restrict__ blockSums, int* __restrict__ blockOffs, int nb) {
    __shared__ int sdata[128];
    int t = threadIdx.x;
    int v = (t < nb) ? blockSums[t] : 0;
    sdata[t] = v;
    __syncthreads();
    for (int d = 1; d < 128; d <<= 1) {
        int u = (t >= d) ? sdata[t - d] : 0;
        __syncthreads();
        sdata[t] += u;
        __syncthreads();
    }
    if (t < nb) blockOffs[t] = sdata[t] - v;
}

// finalize rowptr and seed cursor = rowptr
__global__ void scan3_kernel(int* __restrict__ rowptr, int* __restrict__ cursor,
                             const int* __restrict__ blockOffs, int N, int E) {
    int i = blockIdx.x * blockDim.x + threadIdx.x;
    if (i < N) {
        int r = rowptr[i] + blockOffs[i >> 10];
        rowptr[i] = r;
        cursor[i] = r;
    }
    if (i == 0) rowptr[N] = E;
}

// writes ONLY csr_src (4B/edge) — norm recomputed in agg from dis[]
__global__ void scatter_kernel(const int* __restrict__ edges,
                               int* __restrict__ cursor,
                               int* __restrict__ csr_src, int E) {
    int i = blockIdx.x * blockDim.x + threadIdx.x;
    if (i < E) {
        int s = edges[i];
        int d = edges[E + i];
        int pos = atomicAdd(&cursor[d], 1);
        csr_src[pos] = s;
    }
}

// W transpose + fp32->fp16: Wt[n][k] = W[k][n], for both layer weights
__global__ void wprep_kernel(const float* __restrict__ W1, const float* __restrict__ W2,
                             _Float16* __restrict__ Wt1, _Float16* __restrict__ Wt2) {
    int i = blockIdx.x * blockDim.x + threadIdx.x;  // 0..16383
    int n = i >> 7, k = i & 127;
    Wt1[i] = (_Float16)W1[k * 128 + n];
    Wt2[i] = (_Float16)W2[k * 128 + n];
}

// Y[N,128] = X[N,128] @ W[128,128] via fp16 MFMA (fp32 accum), fp16 out.
// Block: 256 thr (4 waves), 64 rows. Wave w: rows [w*16, w*16+16) x all 128 cols.
// A[m=lane&15][k=quad*8+j]; B (=Wt[n][k]) same with n=lane&15; C/D col=lane&15,row=quad*4+reg.
template <bool HALF_IN>
__global__ void __launch_bounds__(256) gemm_mfma_kernel(const void* __restrict__ Xv,
                                                        const _Float16* __restrict__ WtG,
                                                        _Float16* __restrict__ Y, int N) {
    __shared__ _Float16 wt[128][136];  // Wt staged, +8 pad keeps 16B row alignment
    __shared__ _Float16 xs[64][136];
    int t = threadIdx.x;
    int row0 = blockIdx.x * 64;

    // stage Wt (32KB): 2048 chunks of 8 halves, 8 per thread
#pragma unroll
    for (int i = 0; i < 8; ++i) {
        int c = t + i * 256;
        int r = c >> 4, c8 = (c & 15) * 8;
        *(half8*)&wt[r][c8] = *(const half8*)&WtG[r * 128 + c8];
    }
    // stage X tile (64 rows): thread t -> row t/4, cols (t&3)*32 .. +31
    {
        int r = t >> 2, cb = (t & 3) * 32;
        int grow = row0 + r;
        if (HALF_IN) {
            const _Float16* Xp = (const _Float16*)Xv;
#pragma unroll
            for (int i = 0; i < 4; ++i) {
                half8 v = {};
                if (grow < N) v = *(const half8*)&Xp[(size_t)grow * 128 + cb + i * 8];
                *(half8*)&xs[r][cb + i * 8] = v;
            }
        } else {
            const float* Xp = (const float*)Xv;
#pragma unroll
            for (int i = 0; i < 8; ++i) {
                float4 v = make_float4(0.f, 0.f, 0.f, 0.f);
                if (grow < N) v = *(const float4*)&Xp[(size_t)grow * 128 + cb + i * 4];
                half4 h = {(_Float16)v.x, (_Float16)v.y, (_Float16)v.z, (_Float16)v.w};
                *(half4*)&xs[r][cb + i * 4] = h;
            }
        }
    }
    __syncthreads();

    int wave = t >> 6, lane = t & 63;
    int m = lane & 15, quad = lane >> 4;
    int wrow = wave * 16;

    half8 a[4];
#pragma unroll
    for (int k = 0; k < 4; ++k) a[k] = *(const half8*)&xs[wrow + m][k * 32 + quad * 8];

    floatx4 acc[8];
#pragma unroll
    for (int nt = 0; nt < 8; ++nt) acc[nt] = (floatx4){0.f, 0.f, 0.f, 0.f};
#pragma unroll
    for (int nt = 0; nt < 8; ++nt) {
#pragma unroll
        for (int k = 0; k < 4; ++k) {
            half8 b = *(const half8*)&wt[nt * 16 + m][k * 32 + quad * 8];
            acc[nt] = __builtin_amdgcn_mfma_f32_16x16x32_f16(a[k], b, acc[nt], 0, 0, 0);
        }
    }
#pragma unroll
    for (int nt = 0; nt < 8; ++nt) {
#pragma unroll
        for (int r = 0; r < 4; ++r) {
            int row = row0 + wrow + quad * 4 + r;
            if (row < N) Y[(size_t)row * 128 + nt * 16 + m] = (_Float16)acc[nt][r];
        }
    }
}

// One wave per destination node; lane holds 2 features. norm = dis[s]*dis[v].
__global__ void __launch_bounds__(256) agg_kernel(const _Float16* __restrict__ H,
                                                  const int* __restrict__ rowptr,
                                                  const int* __restrict__ csr_src,
                                                  const float* __restrict__ dis,
                                                  const float* __restrict__ bias,
                                                  _Float16* __restrict__ out, int N) {
    int v = (blockIdx.x * blockDim.x + threadIdx.x) >> 6;
    int lane = threadIdx.x & 63;
    if (v >= N) return;
    int r0 = rowptr[v], r1 = rowptr[v + 1];
    float dv = dis[v];
    half2v hv = ((const half2v*)(H + (size_t)v * 128))[lane];
    float ax = dv * dv * (float)hv.x;
    float ay = dv * dv * (float)hv.y;
    int e = r0;
    for (; e + 4 <= r1; e += 4) {
        int s0 = csr_src[e], s1 = csr_src[e + 1], s2 = csr_src[e + 2], s3 = csr_src[e + 3];
        float w0 = dis[s0] * dv, w1 = dis[s1] * dv, w2 = dis[s2] * dv, w3 = dis[s3] * dv;
        half2v a = ((const half2v*)(H + (size_t)s0 * 128))[lane];
        half2v b = ((const half2v*)(H + (size_t)s1 * 128))[lane];
        half2v c = ((const half2v*)(H + (size_t)s2 * 128))[lane];
        half2v d = ((const half2v*)(H + (size_t)s3 * 128))[lane];
        ax += w0 * (float)a.x + w1 * (float)b.x + w2 * (float)c.x + w3 * (float)d.x;
        ay += w0 * (float)a.y + w1 * (float)b.y + w2 * (float)c.y + w3 * (float)d.y;
    }
    for (; e < r1; ++e) {
        int s0 = csr_src[e];
        float w0 = dis[s0] * dv;
        half2v a = ((const half2v*)(H + (size_t)s0 * 128))[lane];
        ax += w0 * (float)a.x;
        ay += w0 * (float)a.y;
    }
    float2 b = ((const float2*)bias)[lane];
    float ox = fmaxf(ax + b.x, 0.f);
    float oy = fmaxf(ay + b.y, 0.f);
    half2v o = {(_Float16)ox, (_Float16)oy};
    ((half2v*)(out + (size_t)v * 128))[lane] = o;
}

__device__ __forceinline__ int lower_bound_i(const int* a, int n, int key) {
    int lo = 0, hi = n;
    while (lo < hi) {
        int mid = (lo + hi) >> 1;
        if (a[mid] < key) lo = mid + 1;
        else hi = mid;
    }
    return lo;
}

// one block (128 thr) per graph; batch is sorted
__global__ void pool_kernel(const _Float16* __restrict__ H, const int* __restrict__ batch,
                            float* __restrict__ pooled, int N) {
    __shared__ int range[2];
    int g = blockIdx.x;
    if (threadIdx.x == 0) range[0] = lower_bound_i(batch, N, g);
    if (threadIdx.x == 1) range[1] = lower_bound_i(batch, N, g + 1);
    __syncthreads();
    int lo = range[0], hi = range[1];
    int j = threadIdx.x;
    float s = 0.f;
    for (int v = lo; v < hi; ++v) s += (float)H[(size_t)v * 128 + j];
    float cnt = (float)(hi - lo);
    pooled[g * 128 + j] = s / fmaxf(cnt, 1.0f);
}

// one block (128 thr) per graph: relu(pooled@fc1+b1) @ fc2 + b2 -> log_softmax(2)
__global__ void head_kernel(const float* __restrict__ pooled, const float* __restrict__ fc1w,
                            const float* __restrict__ fc1b, const float* __restrict__ fc2w,
                            const float* __restrict__ fc2b, float* __restrict__ out) {
    __shared__ float p[128];
    __shared__ float r0[128], r1[128];
    int g = blockIdx.x;
    int j = threadIdx.x;
    p[j] = pooled[g * 128 + j];
    __syncthreads();
    float acc = fc1b[j];
    for (int k = 0; k < 128; ++k) acc = fmaf(p[k], fc1w[k * 128 + j], acc);
    float gv = fmaxf(acc, 0.f);
    r0[j] = gv * fc2w[j * 2 + 0];
    r1[j] = gv * fc2w[j * 2 + 1];
    __syncthreads();
    for (int s = 64; s > 0; s >>= 1) {
        if (j < s) {
            r0[j] += r0[j + s];
            r1[j] += r1[j + s];
        }
        __syncthreads();
    }
    if (j == 0) {
        float l0 = r0[0] + fc2b[0];
        float l1 = r1[0] + fc2b[1];
        float m = fmaxf(l0, l1);
        float lse = m + logf(expf(l0 - m) + expf(l1 - m));
        out[g * 2 + 0] = l0 - lse;
        out[g * 2 + 1] = l1 - lse;
    }
}

extern "C" void kernel_launch(void* const* d_in, const int* in_sizes, int n_in,
                              void* d_out, int out_size, void* d_ws, size_t ws_size,
                              hipStream_t stream) {
    const float* x    = (const float*)d_in[0];
    const int* edges  = (const int*)d_in[1];
    const int* batch  = (const int*)d_in[2];
    const float* W1   = (const float*)d_in[3];
    const float* b1   = (const float*)d_in[4];
    const float* W2   = (const float*)d_in[5];
    const float* b2   = (const float*)d_in[6];
    const float* fc1w = (const float*)d_in[7];
    const float* fc1b = (const float*)d_in[8];
    const float* fc2w = (const float*)d_in[9];
    const float* fc2b = (const float*)d_in[10];
    float* out = (float*)d_out;

    int N = in_sizes[2];        // 100000
    int E = in_sizes[1] / 2;    // 1600000
    int G = out_size / 2;       // 1024

    char* ws = (char*)d_ws;
    size_t off = 0;
    auto alloc = [&](size_t bytes) -> char* {
        char* ptr = ws + off;
        off += (bytes + 255) & ~(size_t)255;
        return ptr;
    };
    int* counts      = (int*)alloc((size_t)N * 4);
    float* dis       = (float*)alloc((size_t)N * 4);
    int* rowptr      = (int*)alloc((size_t)(N + 1) * 4);
    int* cursor      = (int*)alloc((size_t)N * 4);
    int* csr_src     = (int*)alloc((size_t)E * 4);
    int* blockSums   = (int*)alloc(1024 * 4);
    int* blockOffs   = (int*)alloc(1024 * 4);
    _Float16* Wt1    = (_Float16*)alloc(128 * 128 * 2);
    _Float16* Wt2    = (_Float16*)alloc(128 * 128 * 2);
    _Float16* bufA   = (_Float16*)alloc((size_t)N * D_FEAT * 2);
    _Float16* bufB   = (_Float16*)alloc((size_t)N * D_FEAT * 2);
    float* pooled    = (float*)alloc((size_t)G * D_FEAT * 4);

    hipMemsetAsync(counts, 0, (size_t)N * 4, stream);

    const int tb = 256;
    int gE = (E + tb - 1) / tb;
    int gN = (N + tb - 1) / tb;
    int nb = (N + 1023) / 1024;  // <=128 required by scan2

    hist_kernel<<<gE, tb, 0, stream>>>(edges, counts, E);
    dis_kernel<<<gN, tb, 0, stream>>>(counts, dis, N);
    scan1_kernel<<<nb, 256, 0, stream>>>(counts, rowptr, blockSums, N);
    scan2_kernel<<<1, 128, 0, stream>>>(blockSums, blockOffs, nb);
    scan3_kernel<<<gN, tb, 0, stream>>>(rowptr, cursor, blockOffs, N, E);
    scatter_kernel<<<gE, tb, 0, stream>>>(edges, cursor, csr_src, E);
    wprep_kernel<<<64, 256, 0, stream>>>(W1, W2, Wt1, Wt2);

    int gAgg = (N * 64 + tb - 1) / tb;
    int gGemm = (N + 63) / 64;
    gemm_mfma_kernel<false><<<gGemm, 256, 0, stream>>>((const void*)x, Wt1, bufA, N);
    agg_kernel<<<gAgg, tb, 0, stream>>>(bufA, rowptr, csr_src, dis, b1, bufB, N);
    gemm_mfma_kernel<true><<<gGemm, 256, 0, stream>>>((const void*)bufB, Wt2, bufA, N);
    agg_kernel<<<gAgg, tb, 0, stream>>>(bufA, rowptr, csr_src, dis, b2, bufB, N);
    pool_kernel<<<G, 128, 0, stream>>>(bufB, batch, pooled, N);
    head_kernel<<<G, 128, 0, stream>>>(pooled, fc1w, fc1b, fc2w, fc2b, out);
}

// Round 4
// 387.622 us; speedup vs baseline: 2.0132x; 1.3592x over previous
//
#include <hip/hip_runtime.h>
#include <hip/hip_fp16.h>
#include <math.h>

// GCN: h1 = relu(Agg(x@W1)+b1); h2 = relu(Agg(h1@W2)+b2); pooled = segment_mean(h2);
// out = log_softmax(relu(pooled@fc1+b)@fc2+b)
// Activations fp16 (halves gather BW); GEMMs fp16 MFMA w/ fp32 accum.
// CSR build via 2-level binning (bucket = dst>>9) so csr_src lines are written
// by a single CU in a tight window -> ~1x write amplification (was 16.5x).
// binB also derives degree/rowptr/dis, eliminating the old hist+scan kernels.

#define D_FEAT 128
#define BSHIFT 9
#define BNODES 512          // nodes per bucket
#define CHUNK 4096          // edges per binning block
#define CAP 10240           // binB LDS staging capacity (bucket avg ~8.2K edges)

using half8   = __attribute__((ext_vector_type(8))) _Float16;
using half4   = __attribute__((ext_vector_type(4))) _Float16;
using half2v  = __attribute__((ext_vector_type(2))) _Float16;
using floatx4 = __attribute__((ext_vector_type(4))) float;

// ---- bucket histogram: LDS-aggregated counts of dst>>BSHIFT ----
__global__ void __launch_bounds__(256) bucket_hist_kernel(const int* __restrict__ edges,
                                                          int* __restrict__ gbucket,
                                                          int E, int nb) {
    __shared__ int h[256];
    int t = threadIdx.x;
    h[t] = 0;
    __syncthreads();
    int c0 = blockIdx.x * CHUNK;
#pragma unroll
    for (int k = 0; k < CHUNK / 256; ++k) {
        int i = c0 + t + k * 256;
        if (i < E) atomicAdd(&h[edges[E + i] >> BSHIFT], 1);
    }
    __syncthreads();
    if (t < nb && h[t] > 0) atomicAdd(&gbucket[t], h[t]);
}

// ---- scan bucket counts -> bucketBase[nb+1]; seed gcur ----
__global__ void bucket_scan_kernel(const int* __restrict__ gbucket, int* __restrict__ bucketBase,
                                   int* __restrict__ gcur, int nb, int E) {
    __shared__ int sdata[256];
    int t = threadIdx.x;
    int v = (t < nb) ? gbucket[t] : 0;
    sdata[t] = v;
    __syncthreads();
    for (int d = 1; d < 256; d <<= 1) {
        int u = (t >= d) ? sdata[t - d] : 0;
        __syncthreads();
        sdata[t] += u;
        __syncthreads();
    }
    int excl = sdata[t] - v;
    if (t < nb) { bucketBase[t] = excl; gcur[t] = excl; }
    if (t == 0) bucketBase[nb] = E;
}

// ---- phase A: bin edges; binned[pos] = (dstlow<<17)|src (src<2^17, dstlow<2^9) ----
__global__ void __launch_bounds__(256) binA_kernel(const int* __restrict__ edges,
                                                   int* __restrict__ gcur,
                                                   int* __restrict__ binned, int E, int nb) {
    __shared__ int h[256];
    __shared__ int cur[256];
    __shared__ int base[256];
    int t = threadIdx.x;
    int c0 = blockIdx.x * CHUNK;
    int sv[CHUNK / 256], bv[CHUNK / 256];
#pragma unroll
    for (int k = 0; k < CHUNK / 256; ++k) {
        int i = c0 + t + k * 256;
        if (i < E) {
            int s = edges[i], d = edges[E + i];
            bv[k] = d >> BSHIFT;
            sv[k] = ((d & (BNODES - 1)) << 17) | s;
        } else bv[k] = -1;
    }
    h[t] = 0;
    __syncthreads();
#pragma unroll
    for (int k = 0; k < CHUNK / 256; ++k)
        if (bv[k] >= 0) atomicAdd(&h[bv[k]], 1);
    __syncthreads();
    if (t < nb && h[t] > 0) base[t] = atomicAdd(&gcur[t], h[t]);
    cur[t] = 0;
    __syncthreads();
#pragma unroll
    for (int k = 0; k < CHUNK / 256; ++k)
        if (bv[k] >= 0) {
            int r = atomicAdd(&cur[bv[k]], 1);
            binned[base[bv[k]] + r] = sv[k];
        }
}

// ---- phase B: per bucket: node hist -> dis/rowptr, then XCD-local csr scatter ----
__global__ void __launch_bounds__(256) binB_kernel(const int* __restrict__ binned,
                                                   const int* __restrict__ bucketBase,
                                                   float* __restrict__ dis,
                                                   int* __restrict__ rowptr,
                                                   int* __restrict__ csr_src,
                                                   int N, int E, int nb) {
    __shared__ int hist[BNODES];
    __shared__ int cursorA[BNODES];
    __shared__ int sdata[256];
    __shared__ int vals[CAP];
    int t = threadIdx.x;
    int b = blockIdx.x;
    int node0 = b << BSHIFT;
    int e0 = bucketBase[b], e1 = bucketBase[b + 1];
    int cnt = e1 - e0;
    hist[t] = 0; hist[t + 256] = 0;
    __syncthreads();
    for (int i = t; i < cnt; i += 256) {
        int v = binned[e0 + i];
        if (i < CAP) vals[i] = v;
        atomicAdd(&hist[v >> 17], 1);
    }
    __syncthreads();
    int a0 = hist[2 * t], a1 = hist[2 * t + 1];
    int pair = a0 + a1;
    sdata[t] = pair;
    __syncthreads();
    for (int d = 1; d < 256; d <<= 1) {
        int u = (t >= d) ? sdata[t - d] : 0;
        __syncthreads();
        sdata[t] += u;
        __syncthreads();
    }
    int excl = sdata[t] - pair;
    int p0 = e0 + excl, p1 = e0 + excl + a0;
    cursorA[2 * t] = p0;
    cursorA[2 * t + 1] = p1;
    int n0 = node0 + 2 * t, n1 = node0 + 2 * t + 1;
    if (n0 < N) { rowptr[n0] = p0; dis[n0] = rsqrtf((float)a0 + 1.0f); }
    if (n1 < N) { rowptr[n1] = p1; dis[n1] = rsqrtf((float)a1 + 1.0f); }
    if (b == nb - 1 && t == 0) rowptr[N] = E;
    __syncthreads();
    for (int i = t; i < cnt; i += 256) {
        int v = (i < CAP) ? vals[i] : binned[e0 + i];
        int p = atomicAdd(&cursorA[v >> 17], 1);
        csr_src[p] = v & 0x1FFFF;
    }
}

// W transpose + fp32->fp16: Wt[n][k] = W[k][n]
__global__ void wprep_kernel(const float* __restrict__ W1, const float* __restrict__ W2,
                             _Float16* __restrict__ Wt1, _Float16* __restrict__ Wt2) {
    int i = blockIdx.x * blockDim.x + threadIdx.x;  // 0..16383
    int n = i >> 7, k = i & 127;
    Wt1[i] = (_Float16)W1[k * 128 + n];
    Wt2[i] = (_Float16)W2[k * 128 + n];
}

// Y[N,128] = X[N,128] @ W[128,128] via fp16 MFMA (fp32 accum), fp16 out.
template <bool HALF_IN>
__global__ void __launch_bounds__(256) gemm_mfma_kernel(const void* __restrict__ Xv,
                                                        const _Float16* __restrict__ WtG,
                                                        _Float16* __restrict__ Y, int N) {
    __shared__ _Float16 wt[128][136];
    __shared__ _Float16 xs[64][136];
    int t = threadIdx.x;
    int row0 = blockIdx.x * 64;

#pragma unroll
    for (int i = 0; i < 8; ++i) {
        int c = t + i * 256;
        int r = c >> 4, c8 = (c & 15) * 8;
        *(half8*)&wt[r][c8] = *(const half8*)&WtG[r * 128 + c8];
    }
    {
        int r = t >> 2, cb = (t & 3) * 32;
        int grow = row0 + r;
        if (HALF_IN) {
            const _Float16* Xp = (const _Float16*)Xv;
#pragma unroll
            for (int i = 0; i < 4; ++i) {
                half8 v = {};
                if (grow < N) v = *(const half8*)&Xp[(size_t)grow * 128 + cb + i * 8];
                *(half8*)&xs[r][cb + i * 8] = v;
            }
        } else {
            const float* Xp = (const float*)Xv;
#pragma unroll
            for (int i = 0; i < 8; ++i) {
                float4 v = make_float4(0.f, 0.f, 0.f, 0.f);
                if (grow < N) v = *(const float4*)&Xp[(size_t)grow * 128 + cb + i * 4];
                half4 h = {(_Float16)v.x, (_Float16)v.y, (_Float16)v.z, (_Float16)v.w};
                *(half4*)&xs[r][cb + i * 4] = h;
            }
        }
    }
    __syncthreads();

    int wave = t >> 6, lane = t & 63;
    int m = lane & 15, quad = lane >> 4;
    int wrow = wave * 16;

    half8 a[4];
#pragma unroll
    for (int k = 0; k < 4; ++k) a[k] = *(const half8*)&xs[wrow + m][k * 32 + quad * 8];

    floatx4 acc[8];
#pragma unroll
    for (int nt = 0; nt < 8; ++nt) acc[nt] = (floatx4){0.f, 0.f, 0.f, 0.f};
#pragma unroll
    for (int nt = 0; nt < 8; ++nt) {
#pragma unroll
        for (int k = 0; k < 4; ++k) {
            half8 bfr = *(const half8*)&wt[nt * 16 + m][k * 32 + quad * 8];
            acc[nt] = __builtin_amdgcn_mfma_f32_16x16x32_f16(a[k], bfr, acc[nt], 0, 0, 0);
        }
    }
#pragma unroll
    for (int nt = 0; nt < 8; ++nt) {
#pragma unroll
        for (int r = 0; r < 4; ++r) {
            int row = row0 + wrow + quad * 4 + r;
            if (row < N) Y[(size_t)row * 128 + nt * 16 + m] = (_Float16)acc[nt][r];
        }
    }
}

// One wave per destination node; lane holds 2 features. norm = dis[s]*dis[v].
__global__ void __launch_bounds__(256) agg_kernel(const _Float16* __restrict__ H,
                                                  const int* __restrict__ rowptr,
                                                  const int* __restrict__ csr_src,
                                                  const float* __restrict__ dis,
                                                  const float* __restrict__ bias,
                                                  _Float16* __restrict__ out, int N) {
    int v = (blockIdx.x * blockDim.x + threadIdx.x) >> 6;
    int lane = threadIdx.x & 63;
    if (v >= N) return;
    int r0 = rowptr[v], r1 = rowptr[v + 1];
    float dv = dis[v];
    half2v hv = ((const half2v*)(H + (size_t)v * 128))[lane];
    float ax = dv * dv * (float)hv.x;
    float ay = dv * dv * (float)hv.y;
    int e = r0;
    for (; e + 4 <= r1; e += 4) {
        int s0 = csr_src[e], s1 = csr_src[e + 1], s2 = csr_src[e + 2], s3 = csr_src[e + 3];
        float w0 = dis[s0] * dv, w1 = dis[s1] * dv, w2 = dis[s2] * dv, w3 = dis[s3] * dv;
        half2v a = ((const half2v*)(H + (size_t)s0 * 128))[lane];
        half2v b = ((const half2v*)(H + (size_t)s1 * 128))[lane];
        half2v c = ((const half2v*)(H + (size_t)s2 * 128))[lane];
        half2v d = ((const half2v*)(H + (size_t)s3 * 128))[lane];
        ax += w0 * (float)a.x + w1 * (float)b.x + w2 * (float)c.x + w3 * (float)d.x;
        ay += w0 * (float)a.y + w1 * (float)b.y + w2 * (float)c.y + w3 * (float)d.y;
    }
    for (; e < r1; ++e) {
        int s0 = csr_src[e];
        float w0 = dis[s0] * dv;
        half2v a = ((const half2v*)(H + (size_t)s0 * 128))[lane];
        ax += w0 * (float)a.x;
        ay += w0 * (float)a.y;
    }
    float2 b = ((const float2*)bias)[lane];
    float ox = fmaxf(ax + b.x, 0.f);
    float oy = fmaxf(ay + b.y, 0.f);
    half2v o = {(_Float16)ox, (_Float16)oy};
    ((half2v*)(out + (size_t)v * 128))[lane] = o;
}

__device__ __forceinline__ int lower_bound_i(const int* a, int n, int key) {
    int lo = 0, hi = n;
    while (lo < hi) {
        int mid = (lo + hi) >> 1;
        if (a[mid] < key) lo = mid + 1;
        else hi = mid;
    }
    return lo;
}

// one block (128 thr) per graph; batch is sorted
__global__ void pool_kernel(const _Float16* __restrict__ H, const int* __restrict__ batch,
                            float* __restrict__ pooled, int N) {
    __shared__ int range[2];
    int g = blockIdx.x;
    if (threadIdx.x == 0) range[0] = lower_bound_i(batch, N, g);
    if (threadIdx.x == 1) range[1] = lower_bound_i(batch, N, g + 1);
    __syncthreads();
    int lo = range[0], hi = range[1];
    int j = threadIdx.x;
    float s = 0.f;
    for (int v = lo; v < hi; ++v) s += (float)H[(size_t)v * 128 + j];
    float cnt = (float)(hi - lo);
    pooled[g * 128 + j] = s / fmaxf(cnt, 1.0f);
}

// one block (128 thr) per graph: relu(pooled@fc1+b1) @ fc2 + b2 -> log_softmax(2)
__global__ void head_kernel(const float* __restrict__ pooled, const float* __restrict__ fc1w,
                            const float* __restrict__ fc1b, const float* __restrict__ fc2w,
                            const float* __restrict__ fc2b, float* __restrict__ out) {
    __shared__ float p[128];
    __shared__ float r0[128], r1[128];
    int g = blockIdx.x;
    int j = threadIdx.x;
    p[j] = pooled[g * 128 + j];
    __syncthreads();
    float acc = fc1b[j];
    for (int k = 0; k < 128; ++k) acc = fmaf(p[k], fc1w[k * 128 + j], acc);
    float gv = fmaxf(acc, 0.f);
    r0[j] = gv * fc2w[j * 2 + 0];
    r1[j] = gv * fc2w[j * 2 + 1];
    __syncthreads();
    for (int s = 64; s > 0; s >>= 1) {
        if (j < s) {
            r0[j] += r0[j + s];
            r1[j] += r1[j + s];
        }
        __syncthreads();
    }
    if (j == 0) {
        float l0 = r0[0] + fc2b[0];
        float l1 = r1[0] + fc2b[1];
        float m = fmaxf(l0, l1);
        float lse = m + logf(expf(l0 - m) + expf(l1 - m));
        out[g * 2 + 0] = l0 - lse;
        out[g * 2 + 1] = l1 - lse;
    }
}

extern "C" void kernel_launch(void* const* d_in, const int* in_sizes, int n_in,
                              void* d_out, int out_size, void* d_ws, size_t ws_size,
                              hipStream_t stream) {
    const float* x    = (const float*)d_in[0];
    const int* edges  = (const int*)d_in[1];
    const int* batch  = (const int*)d_in[2];
    const float* W1   = (const float*)d_in[3];
    const float* b1   = (const float*)d_in[4];
    const float* W2   = (const float*)d_in[5];
    const float* b2   = (const float*)d_in[6];
    const float* fc1w = (const float*)d_in[7];
    const float* fc1b = (const float*)d_in[8];
    const float* fc2w = (const float*)d_in[9];
    const float* fc2b = (const float*)d_in[10];
    float* out = (float*)d_out;

    int N = in_sizes[2];        // 100000
    int E = in_sizes[1] / 2;    // 1600000
    int G = out_size / 2;       // 1024
    int nb = (N + BNODES - 1) / BNODES;   // 196 (<=256 required)
    int nA = (E + CHUNK - 1) / CHUNK;     // 391

    char* ws = (char*)d_ws;
    size_t off = 0;
    auto alloc = [&](size_t bytes) -> char* {
        char* ptr = ws + off;
        off += (bytes + 255) & ~(size_t)255;
        return ptr;
    };
    int* gbucket     = (int*)alloc((size_t)nb * 4);
    int* bucketBase  = (int*)alloc((size_t)(nb + 1) * 4);
    int* gcur        = (int*)alloc((size_t)nb * 4);
    int* binned      = (int*)alloc((size_t)E * 4);
    int* rowptr      = (int*)alloc((size_t)(N + 1) * 4);
    float* dis       = (float*)alloc((size_t)N * 4);
    int* csr_src     = (int*)alloc((size_t)E * 4);
    _Float16* Wt1    = (_Float16*)alloc(128 * 128 * 2);
    _Float16* Wt2    = (_Float16*)alloc(128 * 128 * 2);
    _Float16* bufA   = (_Float16*)alloc((size_t)N * D_FEAT * 2);
    _Float16* bufB   = (_Float16*)alloc((size_t)N * D_FEAT * 2);
    float* pooled    = (float*)alloc((size_t)G * D_FEAT * 4);

    hipMemsetAsync(gbucket, 0, (size_t)nb * 4, stream);

    bucket_hist_kernel<<<nA, 256, 0, stream>>>(edges, gbucket, E, nb);
    bucket_scan_kernel<<<1, 256, 0, stream>>>(gbucket, bucketBase, gcur, nb, E);
    binA_kernel<<<nA, 256, 0, stream>>>(edges, gcur, binned, E, nb);
    binB_kernel<<<nb, 256, 0, stream>>>(binned, bucketBase, dis, rowptr, csr_src, N, E, nb);
    wprep_kernel<<<64, 256, 0, stream>>>(W1, W2, Wt1, Wt2);

    const int tb = 256;
    int gAgg = (N * 64 + tb - 1) / tb;
    int gGemm = (N + 63) / 64;
    gemm_mfma_kernel<false><<<gGemm, 256, 0, stream>>>((const void*)x, Wt1, bufA, N);
    agg_kernel<<<gAgg, tb, 0, stream>>>(bufA, rowptr, csr_src, dis, b1, bufB, N);
    gemm_mfma_kernel<true><<<gGemm, 256, 0, stream>>>((const void*)bufB, Wt2, bufA, N);
    agg_kernel<<<gAgg, tb, 0, stream>>>(bufA, rowptr, csr_src, dis, b2, bufB, N);
    pool_kernel<<<G, 128, 0, stream>>>(bufB, batch, pooled, N);
    head_kernel<<<G, 128, 0, stream>>>(pooled, fc1w, fc1b, fc2w, fc2b, out);
}

// Round 5
// 346.486 us; speedup vs baseline: 2.2522x; 1.1187x over previous
//
#include <hip/hip_runtime.h>
#include <hip/hip_fp16.h>
#include <math.h>

// GCN: h1 = relu(Agg(x@W1)+b1); h2 = relu(Agg(h1@W2)+b2); pooled = segment_mean(h2);
// out = log_softmax(relu(pooled@fc1+b)@fc2+b)
// Gather targets (GEMM outputs) stored fp8 e4m3 (128B/row) -> halves agg gather bytes.
// Agg math fp32, agg outputs fp16 (read linearly by gemm2/pool). CSR build via
// 2-level binning (bucket = dst>>9) for ~1x write amplification.

#define D_FEAT 128
#define BSHIFT 9
#define BNODES 512
#define CHUNK 4096
#define CAP 10240

using half8   = __attribute__((ext_vector_type(8))) _Float16;
using half4   = __attribute__((ext_vector_type(4))) _Float16;
using floatx4 = __attribute__((ext_vector_type(4))) float;
using floatx2 = __attribute__((ext_vector_type(2))) float;

// ---- bucket histogram ----
__global__ void __launch_bounds__(256) bucket_hist_kernel(const int* __restrict__ edges,
                                                          int* __restrict__ gbucket,
                                                          int E, int nb) {
    __shared__ int h[256];
    int t = threadIdx.x;
    h[t] = 0;
    __syncthreads();
    int c0 = blockIdx.x * CHUNK;
#pragma unroll
    for (int k = 0; k < CHUNK / 256; ++k) {
        int i = c0 + t + k * 256;
        if (i < E) atomicAdd(&h[edges[E + i] >> BSHIFT], 1);
    }
    __syncthreads();
    if (t < nb && h[t] > 0) atomicAdd(&gbucket[t], h[t]);
}

__global__ void bucket_scan_kernel(const int* __restrict__ gbucket, int* __restrict__ bucketBase,
                                   int* __restrict__ gcur, int nb, int E) {
    __shared__ int sdata[256];
    int t = threadIdx.x;
    int v = (t < nb) ? gbucket[t] : 0;
    sdata[t] = v;
    __syncthreads();
    for (int d = 1; d < 256; d <<= 1) {
        int u = (t >= d) ? sdata[t - d] : 0;
        __syncthreads();
        sdata[t] += u;
        __syncthreads();
    }
    int excl = sdata[t] - v;
    if (t < nb) { bucketBase[t] = excl; gcur[t] = excl; }
    if (t == 0) bucketBase[nb] = E;
}

// ---- phase A: bin edges; binned = (dstlow<<17)|src ----
__global__ void __launch_bounds__(256) binA_kernel(const int* __restrict__ edges,
                                                   int* __restrict__ gcur,
                                                   int* __restrict__ binned, int E, int nb) {
    __shared__ int h[256];
    __shared__ int cur[256];
    __shared__ int base[256];
    int t = threadIdx.x;
    int c0 = blockIdx.x * CHUNK;
    int sv[CHUNK / 256], bv[CHUNK / 256];
#pragma unroll
    for (int k = 0; k < CHUNK / 256; ++k) {
        int i = c0 + t + k * 256;
        if (i < E) {
            int s = edges[i], d = edges[E + i];
            bv[k] = d >> BSHIFT;
            sv[k] = ((d & (BNODES - 1)) << 17) | s;
        } else bv[k] = -1;
    }
    h[t] = 0;
    __syncthreads();
#pragma unroll
    for (int k = 0; k < CHUNK / 256; ++k)
        if (bv[k] >= 0) atomicAdd(&h[bv[k]], 1);
    __syncthreads();
    if (t < nb && h[t] > 0) base[t] = atomicAdd(&gcur[t], h[t]);
    cur[t] = 0;
    __syncthreads();
#pragma unroll
    for (int k = 0; k < CHUNK / 256; ++k)
        if (bv[k] >= 0) {
            int r = atomicAdd(&cur[bv[k]], 1);
            binned[base[bv[k]] + r] = sv[k];
        }
}

// ---- phase B: per bucket: hist -> dis/rowptr, XCD-local csr scatter ----
__global__ void __launch_bounds__(256) binB_kernel(const int* __restrict__ binned,
                                                   const int* __restrict__ bucketBase,
                                                   float* __restrict__ dis,
                                                   int* __restrict__ rowptr,
                                                   int* __restrict__ csr_src,
                                                   int N, int E, int nb) {
    __shared__ int hist[BNODES];
    __shared__ int cursorA[BNODES];
    __shared__ int sdata[256];
    __shared__ int vals[CAP];
    int t = threadIdx.x;
    int b = blockIdx.x;
    int node0 = b << BSHIFT;
    int e0 = bucketBase[b], e1 = bucketBase[b + 1];
    int cnt = e1 - e0;
    hist[t] = 0; hist[t + 256] = 0;
    __syncthreads();
    for (int i = t; i < cnt; i += 256) {
        int v = binned[e0 + i];
        if (i < CAP) vals[i] = v;
        atomicAdd(&hist[v >> 17], 1);
    }
    __syncthreads();
    int a0 = hist[2 * t], a1 = hist[2 * t + 1];
    int pair = a0 + a1;
    sdata[t] = pair;
    __syncthreads();
    for (int d = 1; d < 256; d <<= 1) {
        int u = (t >= d) ? sdata[t - d] : 0;
        __syncthreads();
        sdata[t] += u;
        __syncthreads();
    }
    int excl = sdata[t] - pair;
    int p0 = e0 + excl, p1 = e0 + excl + a0;
    cursorA[2 * t] = p0;
    cursorA[2 * t + 1] = p1;
    int n0 = node0 + 2 * t, n1 = node0 + 2 * t + 1;
    if (n0 < N) { rowptr[n0] = p0; dis[n0] = rsqrtf((float)a0 + 1.0f); }
    if (n1 < N) { rowptr[n1] = p1; dis[n1] = rsqrtf((float)a1 + 1.0f); }
    if (b == nb - 1 && t == 0) rowptr[N] = E;
    __syncthreads();
    for (int i = t; i < cnt; i += 256) {
        int v = (i < CAP) ? vals[i] : binned[e0 + i];
        int p = atomicAdd(&cursorA[v >> 17], 1);
        csr_src[p] = v & 0x1FFFF;
    }
}

// W transpose + fp32->fp16
__global__ void wprep_kernel(const float* __restrict__ W1, const float* __restrict__ W2,
                             _Float16* __restrict__ Wt1, _Float16* __restrict__ Wt2) {
    int i = blockIdx.x * blockDim.x + threadIdx.x;
    int n = i >> 7, k = i & 127;
    Wt1[i] = (_Float16)W1[k * 128 + n];
    Wt2[i] = (_Float16)W2[k * 128 + n];
}

// Y8[N,128] = fp8_e4m3( X[N,128] @ W[128,128] ) via fp16 MFMA (fp32 accum).
// 512 thr / 128 rows per block; Wt staged once, shared by 8 waves.
template <bool HALF_IN>
__global__ void __launch_bounds__(512) gemm_mfma_kernel(const void* __restrict__ Xv,
                                                        const _Float16* __restrict__ WtG,
                                                        unsigned char* __restrict__ Y8, int N) {
    __shared__ _Float16 wt[128][136];
    __shared__ _Float16 xs[128][136];
    int t = threadIdx.x;
    int row0 = blockIdx.x * 128;

#pragma unroll
    for (int i = 0; i < 4; ++i) {
        int c = t + i * 512;
        int r = c >> 4, c8 = (c & 15) * 8;
        *(half8*)&wt[r][c8] = *(const half8*)&WtG[r * 128 + c8];
    }
    {
        int r = t >> 2, cb = (t & 3) * 32;
        int grow = row0 + r;
        if (HALF_IN) {
            const _Float16* Xp = (const _Float16*)Xv;
#pragma unroll
            for (int i = 0; i < 4; ++i) {
                half8 v = {};
                if (grow < N) v = *(const half8*)&Xp[(size_t)grow * 128 + cb + i * 8];
                *(half8*)&xs[r][cb + i * 8] = v;
            }
        } else {
            const float* Xp = (const float*)Xv;
#pragma unroll
            for (int i = 0; i < 8; ++i) {
                float4 v = make_float4(0.f, 0.f, 0.f, 0.f);
                if (grow < N) v = *(const float4*)&Xp[(size_t)grow * 128 + cb + i * 4];
                half4 h = {(_Float16)v.x, (_Float16)v.y, (_Float16)v.z, (_Float16)v.w};
                *(half4*)&xs[r][cb + i * 4] = h;
            }
        }
    }
    __syncthreads();

    int wave = t >> 6, lane = t & 63;
    int m = lane & 15, quad = lane >> 4;
    int wrow = wave * 16;

    half8 a[4];
#pragma unroll
    for (int k = 0; k < 4; ++k) a[k] = *(const half8*)&xs[wrow + m][k * 32 + quad * 8];

    floatx4 acc[8];
#pragma unroll
    for (int nt = 0; nt < 8; ++nt) acc[nt] = (floatx4){0.f, 0.f, 0.f, 0.f};
#pragma unroll
    for (int nt = 0; nt < 8; ++nt) {
#pragma unroll
        for (int k = 0; k < 4; ++k) {
            half8 bfr = *(const half8*)&wt[nt * 16 + m][k * 32 + quad * 8];
            acc[nt] = __builtin_amdgcn_mfma_f32_16x16x32_f16(a[k], bfr, acc[nt], 0, 0, 0);
        }
    }
#pragma unroll
    for (int nt = 0; nt < 8; ++nt) {
#pragma unroll
        for (int r = 0; r < 4; ++r) {
            int row = row0 + wrow + quad * 4 + r;
            if (row < N) {
                float v = acc[nt][r];
                unsigned char q =
                    (unsigned char)(__builtin_amdgcn_cvt_pk_fp8_f32(v, v, 0, false) & 0xff);
                Y8[(size_t)row * 128 + nt * 16 + m] = q;
            }
        }
    }
}

// One wave per dst node over fp8 rows: half-wave (32 lanes x 4B) per edge,
// 2 edges in flight per wave, __shfl_xor(32) combine. Output fp16.
__global__ void __launch_bounds__(256) agg_kernel(const unsigned char* __restrict__ H8,
                                                  const int* __restrict__ rowptr,
                                                  const int* __restrict__ csr_src,
                                                  const float* __restrict__ dis,
                                                  const float* __restrict__ bias,
                                                  _Float16* __restrict__ out, int N) {
    int v = (blockIdx.x * blockDim.x + threadIdx.x) >> 6;
    int lane = threadIdx.x & 63;
    if (v >= N) return;
    int half = lane >> 5, sl = lane & 31;
    int r0 = rowptr[v], r1 = rowptr[v + 1];
    float dv = dis[v];

    float a0, a1, a2, a3;
    {   // self loop: both halves add 0.5*dv^2 (sums to dv^2 after combine)
        float wself = 0.5f * dv * dv;
        unsigned int u = *(const unsigned int*)(H8 + (size_t)v * 128 + sl * 4);
        floatx2 lo = __builtin_amdgcn_cvt_pk_f32_fp8(u, false);
        floatx2 hi = __builtin_amdgcn_cvt_pk_f32_fp8(u, true);
        a0 = wself * lo[0]; a1 = wself * lo[1];
        a2 = wself * hi[0]; a3 = wself * hi[1];
    }
    int e = r0 + half;
    for (; e < r1 - 2; e += 4) {   // this half consumes e and e+2
        int s0 = csr_src[e], s1 = csr_src[e + 2];
        float w0 = dis[s0] * dv, w1 = dis[s1] * dv;
        unsigned int u0 = *(const unsigned int*)(H8 + (size_t)s0 * 128 + sl * 4);
        unsigned int u1 = *(const unsigned int*)(H8 + (size_t)s1 * 128 + sl * 4);
        floatx2 l0 = __builtin_amdgcn_cvt_pk_f32_fp8(u0, false);
        floatx2 h0 = __builtin_amdgcn_cvt_pk_f32_fp8(u0, true);
        floatx2 l1 = __builtin_amdgcn_cvt_pk_f32_fp8(u1, false);
        floatx2 h1 = __builtin_amdgcn_cvt_pk_f32_fp8(u1, true);
        a0 += w0 * l0[0] + w1 * l1[0];
        a1 += w0 * l0[1] + w1 * l1[1];
        a2 += w0 * h0[0] + w1 * h1[0];
        a3 += w0 * h0[1] + w1 * h1[1];
    }
    if (e < r1) {
        int s0 = csr_src[e];
        float w0 = dis[s0] * dv;
        unsigned int u0 = *(const unsigned int*)(H8 + (size_t)s0 * 128 + sl * 4);
        floatx2 l0 = __builtin_amdgcn_cvt_pk_f32_fp8(u0, false);
        floatx2 h0 = __builtin_amdgcn_cvt_pk_f32_fp8(u0, true);
        a0 += w0 * l0[0]; a1 += w0 * l0[1];
        a2 += w0 * h0[0]; a3 += w0 * h0[1];
    }
    a0 += __shfl_xor(a0, 32, 64);
    a1 += __shfl_xor(a1, 32, 64);
    a2 += __shfl_xor(a2, 32, 64);
    a3 += __shfl_xor(a3, 32, 64);
    if (half == 0) {
        float4 b = *(const float4*)&bias[sl * 4];
        half4 o = {(_Float16)fmaxf(a0 + b.x, 0.f), (_Float16)fmaxf(a1 + b.y, 0.f),
                   (_Float16)fmaxf(a2 + b.z, 0.f), (_Float16)fmaxf(a3 + b.w, 0.f)};
        *(half4*)&out[(size_t)v * 128 + sl * 4] = o;
    }
}

__device__ __forceinline__ int lower_bound_i(const int* a, int n, int key) {
    int lo = 0, hi = n;
    while (lo < hi) {
        int mid = (lo + hi) >> 1;
        if (a[mid] < key) lo = mid + 1;
        else hi = mid;
    }
    return lo;
}

// one block (512 thr) per graph; 4 row-groups in parallel + LDS reduce
__global__ void __launch_bounds__(512) pool_kernel(const _Float16* __restrict__ H,
                                                   const int* __restrict__ batch,
                                                   float* __restrict__ pooled, int N) {
    __shared__ int range[2];
    __shared__ float part[4][128];
    int g = blockIdx.x;
    int t = threadIdx.x;
    int j = t & 127, rg = t >> 7;
    if (t < 2) range[t] = lower_bound_i(batch, N, g + t);
    __syncthreads();
    int lo = range[0], hi = range[1];
    float s = 0.f;
    for (int v = lo + rg; v < hi; v += 4) s += (float)H[(size_t)v * 128 + j];
    part[rg][j] = s;
    __syncthreads();
    if (rg == 0) {
        float tot = part[0][j] + part[1][j] + part[2][j] + part[3][j];
        pooled[g * 128 + j] = tot / fmaxf((float)(hi - lo), 1.0f);
    }
}

// one block (128 thr) per graph: relu(pooled@fc1+b1) @ fc2 + b2 -> log_softmax(2)
__global__ void head_kernel(const float* __restrict__ pooled, const float* __restrict__ fc1w,
                            const float* __restrict__ fc1b, const float* __restrict__ fc2w,
                            const float* __restrict__ fc2b, float* __restrict__ out) {
    __shared__ float p[128];
    __shared__ float r0[128], r1[128];
    int g = blockIdx.x;
    int j = threadIdx.x;
    p[j] = pooled[g * 128 + j];
    __syncthreads();
    float acc = fc1b[j];
#pragma unroll 8
    for (int k = 0; k < 128; ++k) acc = fmaf(p[k], fc1w[k * 128 + j], acc);
    float gv = fmaxf(acc, 0.f);
    r0[j] = gv * fc2w[j * 2 + 0];
    r1[j] = gv * fc2w[j * 2 + 1];
    __syncthreads();
    for (int s = 64; s > 0; s >>= 1) {
        if (j < s) {
            r0[j] += r0[j + s];
            r1[j] += r1[j + s];
        }
        __syncthreads();
    }
    if (j == 0) {
        float l0 = r0[0] + fc2b[0];
        float l1 = r1[0] + fc2b[1];
        float m = fmaxf(l0, l1);
        float lse = m + logf(expf(l0 - m) + expf(l1 - m));
        out[g * 2 + 0] = l0 - lse;
        out[g * 2 + 1] = l1 - lse;
    }
}

extern "C" void kernel_launch(void* const* d_in, const int* in_sizes, int n_in,
                              void* d_out, int out_size, void* d_ws, size_t ws_size,
                              hipStream_t stream) {
    const float* x    = (const float*)d_in[0];
    const int* edges  = (const int*)d_in[1];
    const int* batch  = (const int*)d_in[2];
    const float* W1   = (const float*)d_in[3];
    const float* b1   = (const float*)d_in[4];
    const float* W2   = (const float*)d_in[5];
    const float* b2   = (const float*)d_in[6];
    const float* fc1w = (const float*)d_in[7];
    const float* fc1b = (const float*)d_in[8];
    const float* fc2w = (const float*)d_in[9];
    const float* fc2b = (const float*)d_in[10];
    float* out = (float*)d_out;

    int N = in_sizes[2];        // 100000
    int E = in_sizes[1] / 2;    // 1600000
    int G = out_size / 2;       // 1024
    int nb = (N + BNODES - 1) / BNODES;   // 196
    int nA = (E + CHUNK - 1) / CHUNK;     // 391

    char* ws = (char*)d_ws;
    size_t off = 0;
    auto alloc = [&](size_t bytes) -> char* {
        char* ptr = ws + off;
        off += (bytes + 255) & ~(size_t)255;
        return ptr;
    };
    int* gbucket       = (int*)alloc((size_t)nb * 4);
    int* bucketBase    = (int*)alloc((size_t)(nb + 1) * 4);
    int* gcur          = (int*)alloc((size_t)nb * 4);
    int* binned        = (int*)alloc((size_t)E * 4);
    int* rowptr        = (int*)alloc((size_t)(N + 1) * 4);
    float* dis         = (float*)alloc((size_t)N * 4);
    int* csr_src       = (int*)alloc((size_t)E * 4);
    _Float16* Wt1      = (_Float16*)alloc(128 * 128 * 2);
    _Float16* Wt2      = (_Float16*)alloc(128 * 128 * 2);
    unsigned char* buf8 = (unsigned char*)alloc((size_t)N * D_FEAT);      // gather target (both layers)
    _Float16* bufH     = (_Float16*)alloc((size_t)N * D_FEAT * 2);        // agg output (both layers)
    float* pooled      = (float*)alloc((size_t)G * D_FEAT * 4);

    hipMemsetAsync(gbucket, 0, (size_t)nb * 4, stream);

    bucket_hist_kernel<<<nA, 256, 0, stream>>>(edges, gbucket, E, nb);
    bucket_scan_kernel<<<1, 256, 0, stream>>>(gbucket, bucketBase, gcur, nb, E);
    binA_kernel<<<nA, 256, 0, stream>>>(edges, gcur, binned, E, nb);
    binB_kernel<<<nb, 256, 0, stream>>>(binned, bucketBase, dis, rowptr, csr_src, N, E, nb);
    wprep_kernel<<<64, 256, 0, stream>>>(W1, W2, Wt1, Wt2);

    const int tb = 256;
    int gAgg = (N * 64 + tb - 1) / tb;
    int gGemm = (N + 127) / 128;
    gemm_mfma_kernel<false><<<gGemm, 512, 0, stream>>>((const void*)x, Wt1, buf8, N);
    agg_kernel<<<gAgg, tb, 0, stream>>>(buf8, rowptr, csr_src, dis, b1, bufH, N);
    gemm_mfma_kernel<true><<<gGemm, 512, 0, stream>>>((const void*)bufH, Wt2, buf8, N);
    agg_kernel<<<gAgg, tb, 0, stream>>>(buf8, rowptr, csr_src, dis, b2, bufH, N);
    pool_kernel<<<G, 512, 0, stream>>>(bufH, batch, pooled, N);
    head_kernel<<<G, 128, 0, stream>>>(pooled, fc1w, fc1b, fc2w, fc2b, out);
}

// Round 6
// 312.146 us; speedup vs baseline: 2.5000x; 1.1100x over previous
//
#include <hip/hip_runtime.h>
#include <hip/hip_fp16.h>
#include <math.h>

// GCN: h1 = relu(Agg(x@W1)+b1); h2 = relu(Agg(h1@W2)+b2); pooled = segment_mean(h2);
// out = log_softmax(relu(pooled@fc1+b)@fc2+b)
// Gather targets (GEMM outputs) stored fp8 e4m3 (128B/row). Agg math fp32, 4-deep MLP
// per half-wave. CSR build: single-pass binning into fixed-capacity buckets
// (CAPB=16384 >> mean 8163, 90-sigma margin) -> no histogram pre-pass.

#define D_FEAT 128
#define BSHIFT 9
#define BNODES 512
#define CHUNK 4096
#define CAP 10240
#define CAPB 16384

using half8   = __attribute__((ext_vector_type(8))) _Float16;
using half4   = __attribute__((ext_vector_type(4))) _Float16;
using floatx4 = __attribute__((ext_vector_type(4))) float;
using floatx2 = __attribute__((ext_vector_type(2))) float;

// ---- single-pass binning: binned[b*CAPB + pos] = (dstlow<<17)|src ----
__global__ void __launch_bounds__(256) binA_kernel(const int* __restrict__ edges,
                                                   int* __restrict__ gcur,
                                                   int* __restrict__ binned, int E, int nb) {
    __shared__ int h[256];
    __shared__ int cur[256];
    __shared__ int base[256];
    int t = threadIdx.x;
    int c0 = blockIdx.x * CHUNK;
    int sv[CHUNK / 256], bv[CHUNK / 256];
    int i0 = c0 + t * (CHUNK / 256);
    if (i0 + (CHUNK / 256) <= E) {
#pragma unroll
        for (int k = 0; k < CHUNK / 256; k += 4) {
            int4 s4 = *(const int4*)&edges[i0 + k];
            int4 d4 = *(const int4*)&edges[E + i0 + k];
            bv[k + 0] = d4.x >> BSHIFT; sv[k + 0] = ((d4.x & (BNODES - 1)) << 17) | s4.x;
            bv[k + 1] = d4.y >> BSHIFT; sv[k + 1] = ((d4.y & (BNODES - 1)) << 17) | s4.y;
            bv[k + 2] = d4.z >> BSHIFT; sv[k + 2] = ((d4.z & (BNODES - 1)) << 17) | s4.z;
            bv[k + 3] = d4.w >> BSHIFT; sv[k + 3] = ((d4.w & (BNODES - 1)) << 17) | s4.w;
        }
    } else {
#pragma unroll
        for (int k = 0; k < CHUNK / 256; ++k) {
            int i = i0 + k;
            if (i < E) {
                int s = edges[i], d = edges[E + i];
                bv[k] = d >> BSHIFT;
                sv[k] = ((d & (BNODES - 1)) << 17) | s;
            } else bv[k] = -1;
        }
    }
    h[t] = 0;
    __syncthreads();
#pragma unroll
    for (int k = 0; k < CHUNK / 256; ++k)
        if (bv[k] >= 0) atomicAdd(&h[bv[k]], 1);
    __syncthreads();
    if (t < nb && h[t] > 0) base[t] = atomicAdd(&gcur[t], h[t]);
    cur[t] = 0;
    __syncthreads();
#pragma unroll
    for (int k = 0; k < CHUNK / 256; ++k)
        if (bv[k] >= 0) {
            int b = bv[k];
            int r = atomicAdd(&cur[b], 1);
            int pos = base[b] + r;
            if (pos < CAPB) binned[b * CAPB + pos] = sv[k];
        }
}

// ---- scan per-bucket counts (gcur) -> global csr bases ----
__global__ void bucket_scan_kernel(const int* __restrict__ gcur, int* __restrict__ bucketBase,
                                   int nb, int E) {
    __shared__ int sdata[256];
    int t = threadIdx.x;
    int v = (t < nb) ? gcur[t] : 0;
    sdata[t] = v;
    __syncthreads();
    for (int d = 1; d < 256; d <<= 1) {
        int u = (t >= d) ? sdata[t - d] : 0;
        __syncthreads();
        sdata[t] += u;
        __syncthreads();
    }
    if (t < nb) bucketBase[t] = sdata[t] - v;
    if (t == 0) bucketBase[nb] = E;
}

// ---- per bucket: node hist -> dis/rowptr, XCD-local csr scatter ----
__global__ void __launch_bounds__(256) binB_kernel(const int* __restrict__ binned,
                                                   const int* __restrict__ bucketBase,
                                                   const int* __restrict__ gcur,
                                                   float* __restrict__ dis,
                                                   int* __restrict__ rowptr,
                                                   int* __restrict__ csr_src,
                                                   int N, int E, int nb) {
    __shared__ int hist[BNODES];
    __shared__ int cursorA[BNODES];
    __shared__ int sdata[256];
    __shared__ int vals[CAP];
    int t = threadIdx.x;
    int b = blockIdx.x;
    int node0 = b << BSHIFT;
    int e0 = bucketBase[b];
    int cnt = gcur[b];
    const int* bin = binned + (size_t)b * CAPB;
    hist[t] = 0; hist[t + 256] = 0;
    __syncthreads();
    for (int i = t; i < cnt; i += 256) {
        int v = bin[i];
        if (i < CAP) vals[i] = v;
        atomicAdd(&hist[v >> 17], 1);
    }
    __syncthreads();
    int a0 = hist[2 * t], a1 = hist[2 * t + 1];
    int pair = a0 + a1;
    sdata[t] = pair;
    __syncthreads();
    for (int d = 1; d < 256; d <<= 1) {
        int u = (t >= d) ? sdata[t - d] : 0;
        __syncthreads();
        sdata[t] += u;
        __syncthreads();
    }
    int excl = sdata[t] - pair;
    int p0 = e0 + excl, p1 = e0 + excl + a0;
    cursorA[2 * t] = p0;
    cursorA[2 * t + 1] = p1;
    int n0 = node0 + 2 * t, n1 = node0 + 2 * t + 1;
    if (n0 < N) { rowptr[n0] = p0; dis[n0] = rsqrtf((float)a0 + 1.0f); }
    if (n1 < N) { rowptr[n1] = p1; dis[n1] = rsqrtf((float)a1 + 1.0f); }
    if (b == nb - 1 && t == 0) rowptr[N] = E;
    __syncthreads();
    for (int i = t; i < cnt; i += 256) {
        int v = (i < CAP) ? vals[i] : bin[i];
        int p = atomicAdd(&cursorA[v >> 17], 1);
        csr_src[p] = v & 0x1FFFF;
    }
}

// W transpose + fp32->fp16
__global__ void wprep_kernel(const float* __restrict__ W1, const float* __restrict__ W2,
                             _Float16* __restrict__ Wt1, _Float16* __restrict__ Wt2) {
    int i = blockIdx.x * blockDim.x + threadIdx.x;
    int n = i >> 7, k = i & 127;
    Wt1[i] = (_Float16)W1[k * 128 + n];
    Wt2[i] = (_Float16)W2[k * 128 + n];
}

// Y8[N,128] = fp8_e4m3( X[N,128] @ W[128,128] ) via fp16 MFMA (fp32 accum).
template <bool HALF_IN>
__global__ void __launch_bounds__(512) gemm_mfma_kernel(const void* __restrict__ Xv,
                                                        const _Float16* __restrict__ WtG,
                                                        unsigned char* __restrict__ Y8, int N) {
    __shared__ _Float16 wt[128][136];
    __shared__ _Float16 xs[128][136];
    int t = threadIdx.x;
    int row0 = blockIdx.x * 128;

#pragma unroll
    for (int i = 0; i < 4; ++i) {
        int c = t + i * 512;
        int r = c >> 4, c8 = (c & 15) * 8;
        *(half8*)&wt[r][c8] = *(const half8*)&WtG[r * 128 + c8];
    }
    {
        int r = t >> 2, cb = (t & 3) * 32;
        int grow = row0 + r;
        if (HALF_IN) {
            const _Float16* Xp = (const _Float16*)Xv;
#pragma unroll
            for (int i = 0; i < 4; ++i) {
                half8 v = {};
                if (grow < N) v = *(const half8*)&Xp[(size_t)grow * 128 + cb + i * 8];
                *(half8*)&xs[r][cb + i * 8] = v;
            }
        } else {
            const float* Xp = (const float*)Xv;
#pragma unroll
            for (int i = 0; i < 8; ++i) {
                float4 v = make_float4(0.f, 0.f, 0.f, 0.f);
                if (grow < N) v = *(const float4*)&Xp[(size_t)grow * 128 + cb + i * 4];
                half4 h = {(_Float16)v.x, (_Float16)v.y, (_Float16)v.z, (_Float16)v.w};
                *(half4*)&xs[r][cb + i * 4] = h;
            }
        }
    }
    __syncthreads();

    int wave = t >> 6, lane = t & 63;
    int m = lane & 15, quad = lane >> 4;
    int wrow = wave * 16;

    half8 a[4];
#pragma unroll
    for (int k = 0; k < 4; ++k) a[k] = *(const half8*)&xs[wrow + m][k * 32 + quad * 8];

    floatx4 acc[8];
#pragma unroll
    for (int nt = 0; nt < 8; ++nt) acc[nt] = (floatx4){0.f, 0.f, 0.f, 0.f};
#pragma unroll
    for (int nt = 0; nt < 8; ++nt) {
#pragma unroll
        for (int k = 0; k < 4; ++k) {
            half8 bfr = *(const half8*)&wt[nt * 16 + m][k * 32 + quad * 8];
            acc[nt] = __builtin_amdgcn_mfma_f32_16x16x32_f16(a[k], bfr, acc[nt], 0, 0, 0);
        }
    }
#pragma unroll
    for (int nt = 0; nt < 8; ++nt) {
#pragma unroll
        for (int r = 0; r < 4; ++r) {
            int row = row0 + wrow + quad * 4 + r;
            if (row < N) {
                float v = acc[nt][r];
                unsigned char q =
                    (unsigned char)(__builtin_amdgcn_cvt_pk_fp8_f32(v, v, 0, false) & 0xff);
                Y8[(size_t)row * 128 + nt * 16 + m] = q;
            }
        }
    }
}

// One wave per dst node over fp8 rows; half-wave per edge, 4 edges/half in flight.
__global__ void __launch_bounds__(256) agg_kernel(const unsigned char* __restrict__ H8,
                                                  const int* __restrict__ rowptr,
                                                  const int* __restrict__ csr_src,
                                                  const float* __restrict__ dis,
                                                  const float* __restrict__ bias,
                                                  _Float16* __restrict__ out, int N) {
    int v = (blockIdx.x * blockDim.x + threadIdx.x) >> 6;
    int lane = threadIdx.x & 63;
    if (v >= N) return;
    int half = lane >> 5, sl = lane & 31;
    int r0 = rowptr[v], r1 = rowptr[v + 1];
    float dv = dis[v];

    float a0, a1, a2, a3;
    {   // self loop: both halves add 0.5*dv^2 (sums to dv^2 after combine)
        float wself = 0.5f * dv * dv;
        unsigned int u = *(const unsigned int*)(H8 + (size_t)v * 128 + sl * 4);
        floatx2 lo = __builtin_amdgcn_cvt_pk_f32_fp8(u, false);
        floatx2 hi = __builtin_amdgcn_cvt_pk_f32_fp8(u, true);
        a0 = wself * lo[0]; a1 = wself * lo[1];
        a2 = wself * hi[0]; a3 = wself * hi[1];
    }
    int e = r0 + half;
    for (; e + 6 < r1; e += 8) {   // 4 edges per half per iter
        int s0 = csr_src[e], s1 = csr_src[e + 2], s2 = csr_src[e + 4], s3 = csr_src[e + 6];
        float w0 = dis[s0] * dv, w1 = dis[s1] * dv, w2 = dis[s2] * dv, w3 = dis[s3] * dv;
        unsigned int u0 = *(const unsigned int*)(H8 + (size_t)s0 * 128 + sl * 4);
        unsigned int u1 = *(const unsigned int*)(H8 + (size_t)s1 * 128 + sl * 4);
        unsigned int u2 = *(const unsigned int*)(H8 + (size_t)s2 * 128 + sl * 4);
        unsigned int u3 = *(const unsigned int*)(H8 + (size_t)s3 * 128 + sl * 4);
        floatx2 l0 = __builtin_amdgcn_cvt_pk_f32_fp8(u0, false);
        floatx2 h0 = __builtin_amdgcn_cvt_pk_f32_fp8(u0, true);
        floatx2 l1 = __builtin_amdgcn_cvt_pk_f32_fp8(u1, false);
        floatx2 h1 = __builtin_amdgcn_cvt_pk_f32_fp8(u1, true);
        floatx2 l2 = __builtin_amdgcn_cvt_pk_f32_fp8(u2, false);
        floatx2 h2 = __builtin_amdgcn_cvt_pk_f32_fp8(u2, true);
        floatx2 l3 = __builtin_amdgcn_cvt_pk_f32_fp8(u3, false);
        floatx2 h3 = __builtin_amdgcn_cvt_pk_f32_fp8(u3, true);
        a0 += w0 * l0[0] + w1 * l1[0] + w2 * l2[0] + w3 * l3[0];
        a1 += w0 * l0[1] + w1 * l1[1] + w2 * l2[1] + w3 * l3[1];
        a2 += w0 * h0[0] + w1 * h1[0] + w2 * h2[0] + w3 * h3[0];
        a3 += w0 * h0[1] + w1 * h1[1] + w2 * h2[1] + w3 * h3[1];
    }
    for (; e < r1; e += 2) {
        int s0 = csr_src[e];
        float w0 = dis[s0] * dv;
        unsigned int u0 = *(const unsigned int*)(H8 + (size_t)s0 * 128 + sl * 4);
        floatx2 l0 = __builtin_amdgcn_cvt_pk_f32_fp8(u0, false);
        floatx2 h0 = __builtin_amdgcn_cvt_pk_f32_fp8(u0, true);
        a0 += w0 * l0[0]; a1 += w0 * l0[1];
        a2 += w0 * h0[0]; a3 += w0 * h0[1];
    }
    a0 += __shfl_xor(a0, 32, 64);
    a1 += __shfl_xor(a1, 32, 64);
    a2 += __shfl_xor(a2, 32, 64);
    a3 += __shfl_xor(a3, 32, 64);
    if (half == 0) {
        float4 b = *(const float4*)&bias[sl * 4];
        half4 o = {(_Float16)fmaxf(a0 + b.x, 0.f), (_Float16)fmaxf(a1 + b.y, 0.f),
                   (_Float16)fmaxf(a2 + b.z, 0.f), (_Float16)fmaxf(a3 + b.w, 0.f)};
        *(half4*)&out[(size_t)v * 128 + sl * 4] = o;
    }
}

__device__ __forceinline__ int lower_bound_i(const int* a, int n, int key) {
    int lo = 0, hi = n;
    while (lo < hi) {
        int mid = (lo + hi) >> 1;
        if (a[mid] < key) lo = mid + 1;
        else hi = mid;
    }
    return lo;
}

// one block (512 thr) per graph; 4 row-groups in parallel + LDS reduce
__global__ void __launch_bounds__(512) pool_kernel(const _Float16* __restrict__ H,
                                                   const int* __restrict__ batch,
                                                   float* __restrict__ pooled, int N) {
    __shared__ int range[2];
    __shared__ float part[4][128];
    int g = blockIdx.x;
    int t = threadIdx.x;
    int j = t & 127, rg = t >> 7;
    if (t < 2) range[t] = lower_bound_i(batch, N, g + t);
    __syncthreads();
    int lo = range[0], hi = range[1];
    float s = 0.f;
    for (int v = lo + rg; v < hi; v += 4) s += (float)H[(size_t)v * 128 + j];
    part[rg][j] = s;
    __syncthreads();
    if (rg == 0) {
        float tot = part[0][j] + part[1][j] + part[2][j] + part[3][j];
        pooled[g * 128 + j] = tot / fmaxf((float)(hi - lo), 1.0f);
    }
}

// one block (128 thr) per graph: relu(pooled@fc1+b1) @ fc2 + b2 -> log_softmax(2)
__global__ void head_kernel(const float* __restrict__ pooled, const float* __restrict__ fc1w,
                            const float* __restrict__ fc1b, const float* __restrict__ fc2w,
                            const float* __restrict__ fc2b, float* __restrict__ out) {
    __shared__ float p[128];
    __shared__ float r0[128], r1[128];
    int g = blockIdx.x;
    int j = threadIdx.x;
    p[j] = pooled[g * 128 + j];
    __syncthreads();
    float acc = fc1b[j];
#pragma unroll 8
    for (int k = 0; k < 128; ++k) acc = fmaf(p[k], fc1w[k * 128 + j], acc);
    float gv = fmaxf(acc, 0.f);
    r0[j] = gv * fc2w[j * 2 + 0];
    r1[j] = gv * fc2w[j * 2 + 1];
    __syncthreads();
    for (int s = 64; s > 0; s >>= 1) {
        if (j < s) {
            r0[j] += r0[j + s];
            r1[j] += r1[j + s];
        }
        __syncthreads();
    }
    if (j == 0) {
        float l0 = r0[0] + fc2b[0];
        float l1 = r1[0] + fc2b[1];
        float m = fmaxf(l0, l1);
        float lse = m + logf(expf(l0 - m) + expf(l1 - m));
        out[g * 2 + 0] = l0 - lse;
        out[g * 2 + 1] = l1 - lse;
    }
}

extern "C" void kernel_launch(void* const* d_in, const int* in_sizes, int n_in,
                              void* d_out, int out_size, void* d_ws, size_t ws_size,
                              hipStream_t stream) {
    const float* x    = (const float*)d_in[0];
    const int* edges  = (const int*)d_in[1];
    const int* batch  = (const int*)d_in[2];
    const float* W1   = (const float*)d_in[3];
    const float* b1   = (const float*)d_in[4];
    const float* W2   = (const float*)d_in[5];
    const float* b2   = (const float*)d_in[6];
    const float* fc1w = (const float*)d_in[7];
    const float* fc1b = (const float*)d_in[8];
    const float* fc2w = (const float*)d_in[9];
    const float* fc2b = (const float*)d_in[10];
    float* out = (float*)d_out;

    int N = in_sizes[2];        // 100000
    int E = in_sizes[1] / 2;    // 1600000
    int G = out_size / 2;       // 1024
    int nb = (N + BNODES - 1) / BNODES;   // 196
    int nA = (E + CHUNK - 1) / CHUNK;     // 391

    char* ws = (char*)d_ws;
    size_t off = 0;
    auto alloc = [&](size_t bytes) -> char* {
        char* ptr = ws + off;
        off += (bytes + 255) & ~(size_t)255;
        return ptr;
    };
    int* gcur          = (int*)alloc((size_t)nb * 4);
    int* bucketBase    = (int*)alloc((size_t)(nb + 1) * 4);
    int* binned        = (int*)alloc((size_t)nb * CAPB * 4);
    int* rowptr        = (int*)alloc((size_t)(N + 1) * 4);
    float* dis         = (float*)alloc((size_t)N * 4);
    int* csr_src       = (int*)alloc((size_t)E * 4);
    _Float16* Wt1      = (_Float16*)alloc(128 * 128 * 2);
    _Float16* Wt2      = (_Float16*)alloc(128 * 128 * 2);
    unsigned char* buf8 = (unsigned char*)alloc((size_t)N * D_FEAT);
    _Float16* bufH     = (_Float16*)alloc((size_t)N * D_FEAT * 2);
    float* pooled      = (float*)alloc((size_t)G * D_FEAT * 4);

    hipMemsetAsync(gcur, 0, (size_t)nb * 4, stream);

    binA_kernel<<<nA, 256, 0, stream>>>(edges, gcur, binned, E, nb);
    bucket_scan_kernel<<<1, 256, 0, stream>>>(gcur, bucketBase, nb, E);
    binB_kernel<<<nb, 256, 0, stream>>>(binned, bucketBase, gcur, dis, rowptr, csr_src, N, E, nb);
    wprep_kernel<<<64, 256, 0, stream>>>(W1, W2, Wt1, Wt2);

    const int tb = 256;
    int gAgg = (N * 64 + tb - 1) / tb;
    int gGemm = (N + 127) / 128;
    gemm_mfma_kernel<false><<<gGemm, 512, 0, stream>>>((const void*)x, Wt1, buf8, N);
    agg_kernel<<<gAgg, tb, 0, stream>>>(buf8, rowptr, csr_src, dis, b1, bufH, N);
    gemm_mfma_kernel<true><<<gGemm, 512, 0, stream>>>((const void*)bufH, Wt2, buf8, N);
    agg_kernel<<<gAgg, tb, 0, stream>>>(buf8, rowptr, csr_src, dis, b2, bufH, N);
    pool_kernel<<<G, 512, 0, stream>>>(bufH, batch, pooled, N);
    head_kernel<<<G, 128, 0, stream>>>(pooled, fc1w, fc1b, fc2w, fc2b, out);
}